// Round 8
// baseline (662.345 us; speedup 1.0000x reference)
//
#include <hip/hip_runtime.h>

#define NN 50000
#define EE 600000
#define CC 128
#define ECC 16
#define LL 4
#define LN_EPS 1e-5f
#define MTILE 80
#define PADC 136   // LDS row stride in bf16 elems for hA/tA
#define YSTR 132   // f32 stride for yS overlay (2-way-free banks)
#define ESTR 132   // LDS row stride (shorts) for per-wave ea tile

typedef float f32x4 __attribute__((ext_vector_type(4)));
typedef short bf16x8 __attribute__((ext_vector_type(8)));

static __device__ __forceinline__ float bf2f(unsigned short u) {
  union { unsigned int i; float f; } v; v.i = ((unsigned int)u) << 16; return v.f;
}
static __device__ __forceinline__ unsigned short f2bf(float f) {
  union { float f; unsigned int i; } v; v.f = f;
  unsigned int b = v.i + 0x7FFFu + ((v.i >> 16) & 1u);
  return (unsigned short)(b >> 16);
}
static __device__ __forceinline__ float silu_f(float v) {
  return v / (1.f + __expf(-v));
}

// ---------------- CSR build ----------------

__global__ void count_kernel(const int* __restrict__ dst, int* __restrict__ counts, int E) {
  int e = blockIdx.x * blockDim.x + threadIdx.x;
  if (e < E) atomicAdd(&counts[dst[e]], 1);
}

__global__ __launch_bounds__(1024) void scan1_kernel(const int* __restrict__ counts,
                                                     int* __restrict__ bsum, int n) {
  __shared__ int wsum[16];
  const int tid = threadIdx.x, lane = tid & 63, wv = tid >> 6;
  const int i = blockIdx.x * 1024 + tid;
  int s = (i < n) ? counts[i] : 0;
  #pragma unroll
  for (int off = 1; off < 64; off <<= 1) s += __shfl_xor(s, off);
  if (lane == 0) wsum[wv] = s;
  __syncthreads();
  if (tid == 0) {
    int t = 0;
    #pragma unroll
    for (int j = 0; j < 16; ++j) t += wsum[j];
    bsum[blockIdx.x] = t;
  }
}

__global__ void scan2_kernel(const int* __restrict__ bsum, int* __restrict__ boff, int nb) {
  const int lane = threadIdx.x;   // one wave
  int v = (lane < nb) ? bsum[lane] : 0;
  int incl = v;
  #pragma unroll
  for (int off = 1; off < 64; off <<= 1) {
    int t = __shfl_up(incl, off);
    if (lane >= off) incl += t;
  }
  if (lane < nb) boff[lane] = incl - v;
}

__global__ __launch_bounds__(1024) void scan3_kernel(const int* __restrict__ counts,
                                                     const int* __restrict__ boff,
                                                     int* __restrict__ rowptr, int n) {
  __shared__ int wsum[16];
  const int tid = threadIdx.x, lane = tid & 63, wv = tid >> 6;
  const int i = blockIdx.x * 1024 + tid;
  const int v = (i < n) ? counts[i] : 0;
  int incl = v;
  #pragma unroll
  for (int off = 1; off < 64; off <<= 1) {
    int t = __shfl_up(incl, off);
    if (lane >= off) incl += t;
  }
  if (lane == 63) wsum[wv] = incl;
  __syncthreads();
  if (wv == 0) {
    int vv = (lane < 16) ? wsum[lane] : 0;
    int vi = vv;
    #pragma unroll
    for (int off = 1; off < 16; off <<= 1) {
      int t = __shfl_up(vi, off);
      if (lane >= off) vi += t;
    }
    if (lane < 16) wsum[lane] = vi - vv;   // exclusive wave prefix
  }
  __syncthreads();
  if (i < n) rowptr[i + 1] = boff[blockIdx.x] + wsum[wv] + incl;
  if (i == 0) rowptr[0] = 0;
}

__global__ void fill_kernel(const int* __restrict__ src, const int* __restrict__ dst,
                            const int* __restrict__ rowptr, int* __restrict__ cursor,
                            int* __restrict__ eidx, int* __restrict__ esrc, int E) {
  int e = blockIdx.x * blockDim.x + threadIdx.x;
  if (e < E) {
    const int d = dst[e];
    const int pos = rowptr[d] + atomicAdd(&cursor[d], 1);
    eidx[pos] = e;
    esrc[pos] = src[e];
  }
}

// ---------------- edge_attr gather into CSR order (f32) ----------------

__global__ __launch_bounds__(256) void gather_attr_kernel(const float* __restrict__ edge_attr,
                                                          const int* __restrict__ eidx,
                                                          float* __restrict__ attr_csr) {
  const long t = (long)blockIdx.x * 256 + threadIdx.x;
  if (t >= (long)EE * 4) return;
  const int p = (int)(t >> 2), q = (int)(t & 3);
  const int e = eidx[p];
  *(float4*)(attr_csr + (size_t)p * ECC + q * 4) =
      *(const float4*)(edge_attr + (size_t)e * ECC + q * 4);
}

// ---------------- We B-fragment prep (bf16, MFMA fragment order) ----------------
// webf[cg*512 + l*8 + j] = (k<16 ? bf16(We[k][cg*16+(l&15)]) : 0), k=(l>>4)*8+j

__global__ void webconv_kernel(const float* __restrict__ We, unsigned short* __restrict__ webf) {
  const int t = blockIdx.x * blockDim.x + threadIdx.x;
  if (t >= 8 * 64 * 8) return;
  const int j = t & 7, l = (t >> 3) & 63, cg = t >> 9;
  const int k = (l >> 4) * 8 + j, c = cg * 16 + (l & 15);
  webf[t] = (k < 16) ? f2bf(We[k * CC + c]) : (unsigned short)0;
}

// ---------------- weight transpose+cast: wt[l][mat][c][k] = bf16(W[l][k][c]) ----------------

__global__ __launch_bounds__(128) void wconv_kernel(const float* __restrict__ W1,
                                                    const float* __restrict__ W2,
                                                    unsigned short* __restrict__ wt) {
  const int b = blockIdx.x;
  const int c = b & (CC - 1);
  const int mat = (b >> 7) & 1;
  const int l = b >> 8;
  const float* W = (mat ? W2 : W1) + (size_t)l * CC * CC;
  unsigned short* o = wt + ((size_t)l * 2 + mat) * CC * CC + (size_t)c * CC;
  const int k = threadIdx.x;
  o[k] = f2bf(W[(size_t)k * CC + c]);
}

// ---------------- aggregation with in-kernel MFMA ea recompute ----------------
// Wave = one node. Per <=16-edge batch of the node's CSR run:
//   MFMA phase: A = attr rows (f32->bf16, zero-padded), B = webf frags (regs),
//     8x mfma_16x16x32 -> ea tile -> silu+pack -> per-wave LDS [16][ESTR].
//   Accumulate phase (agg4 pattern): half-wave per edge, 4 ch/lane,
//     float4 x-gather + uint2 ea from LDS.
// No __syncthreads anywhere (waves diverge in batch count) - wave-local
// s_waitcnt lgkmcnt(0) orders LDS write->read within the wave.

__global__ __launch_bounds__(256) void agg5_kernel(const float* __restrict__ x_in,
                                                   unsigned short* __restrict__ h_out,
                                                   const float* __restrict__ attr_csr,
                                                   const unsigned short* __restrict__ webf,
                                                   const float* __restrict__ be,
                                                   const int* __restrict__ rowptr,
                                                   const int* __restrict__ esrc) {
  __shared__ unsigned short ealds[4][16 * ESTR];   // 16,896 B
  const int tid = threadIdx.x;
  const int lane = tid & 63;
  const int wv = tid >> 6;
  const int l16 = lane & 15, ko = lane >> 4;
  const int half = lane >> 5, l32 = lane & 31;
  const int c0 = l32 * 4;
  unsigned short* elds = ealds[wv];

  // resident B fragments + bias (col = l16 for every ko group)
  bf16x8 bw[8];
  #pragma unroll
  for (int cg = 0; cg < 8; ++cg)
    bw[cg] = *(const bf16x8*)(webf + cg * 512 + lane * 8);
  float bev[8];
  #pragma unroll
  for (int cg = 0; cg < 8; ++cg) bev[cg] = be[cg * 16 + l16];

  const int n = blockIdx.x * 4 + wv;
  const int p0 = rowptr[n], p1 = rowptr[n + 1];
  float a0 = 0.f, a1 = 0.f, a2 = 0.f, a3 = 0.f;

  for (int pb = p0; pb < p1; pb += 16) {
    const int nb = (p1 - pb < 16) ? (p1 - pb) : 16;

    // ---- MFMA phase: ea[0..nb) for csr positions pb.. ----
    union { unsigned short u[8]; bf16x8 v; } af;
    if (ko < 2 && l16 < nb) {
      const float* ap = attr_csr + (size_t)(pb + l16) * ECC + ko * 8;
      const float4 q0 = *(const float4*)ap;
      const float4 q1 = *(const float4*)(ap + 4);
      af.u[0] = f2bf(q0.x); af.u[1] = f2bf(q0.y);
      af.u[2] = f2bf(q0.z); af.u[3] = f2bf(q0.w);
      af.u[4] = f2bf(q1.x); af.u[5] = f2bf(q1.y);
      af.u[6] = f2bf(q1.z); af.u[7] = f2bf(q1.w);
    } else {
      #pragma unroll
      for (int j = 0; j < 8; ++j) af.u[j] = 0;
    }

    f32x4 acc[8];
    #pragma unroll
    for (int cg = 0; cg < 8; ++cg) {
      acc[cg] = (f32x4)0.f;
      acc[cg] = __builtin_amdgcn_mfma_f32_16x16x32_bf16(af.v, bw[cg], acc[cg], 0, 0, 0);
    }

    // drain prior batch's LDS reads before overwriting the tile
    asm volatile("s_waitcnt lgkmcnt(0)" ::: "memory");

    // C layout: col=l16, row=ko*4+r  ->  banks: ko groups 8 apart, 2-way free
    #pragma unroll
    for (int cg = 0; cg < 8; ++cg)
      #pragma unroll
      for (int r = 0; r < 4; ++r) {
        const float v = acc[cg][r] + bev[cg];
        elds[(ko * 4 + r) * ESTR + cg * 16 + l16] = f2bf(silu_f(v));
      }
    asm volatile("s_waitcnt lgkmcnt(0)" ::: "memory");

    // ---- accumulate phase: half-wave per edge, 4 ch/lane ----
    for (int e = half; e < nb; e += 2) {
      const int p = pb + e;
      const int s = esrc[p];
      const float4 xv = *(const float4*)(x_in + (size_t)s * CC + c0);
      const uint2 ev = *(const uint2*)(elds + e * ESTR + c0);
      a0 += fmaxf(xv.x + bf2f((unsigned short)ev.x), 0.f);
      a1 += fmaxf(xv.y + bf2f((unsigned short)(ev.x >> 16)), 0.f);
      a2 += fmaxf(xv.z + bf2f((unsigned short)ev.y), 0.f);
      a3 += fmaxf(xv.w + bf2f((unsigned short)(ev.y >> 16)), 0.f);
    }
  }

  // combine the two halves (same channels, different edges)
  a0 += __shfl_xor(a0, 32);
  a1 += __shfl_xor(a1, 32);
  a2 += __shfl_xor(a2, 32);
  a3 += __shfl_xor(a3, 32);

  if (half == 0) {
    const float4 xs = *(const float4*)(x_in + (size_t)n * CC + c0);
    uint2 pk;
    pk.x = (unsigned int)f2bf(xs.x + a0) | ((unsigned int)f2bf(xs.y + a1) << 16);
    pk.y = (unsigned int)f2bf(xs.z + a2) | ((unsigned int)f2bf(xs.w + a3) << 16);
    *(uint2*)(h_out + (size_t)n * CC + c0) = pk;
  }
}

// ---------------- aggregation (fallback: small ws, recompute via eidx) ----------------

__global__ __launch_bounds__(256) void agg_fb_kernel(const float* __restrict__ x_in,
                                                     unsigned short* __restrict__ h_out,
                                                     const float* __restrict__ edge_attr,
                                                     const float* __restrict__ We,
                                                     const float* __restrict__ be,
                                                     const int* __restrict__ rowptr,
                                                     const int* __restrict__ eidx,
                                                     const int* __restrict__ esrc) {
  const int tid = threadIdx.x;
  const int c = tid & (CC - 1);
  const int g = tid >> 7;
  const int n = blockIdx.x * 2 + g;

  float wec[ECC];
  #pragma unroll
  for (int k = 0; k < ECC; ++k) wec[k] = We[k * CC + c];
  const float bev = be[c];

  const int p0 = rowptr[n], p1 = rowptr[n + 1];
  float acc = 0.f;
  for (int p = p0; p < p1; ++p) {
    const int e0 = eidx[p];
    const int s0 = esrc[p];
    const float4* ar0 = (const float4*)(edge_attr + (size_t)e0 * ECC);
    const float4 a0 = ar0[0], a1 = ar0[1], a2 = ar0[2], a3 = ar0[3];
    float v0 = bev
      + a0.x*wec[0]  + a0.y*wec[1]  + a0.z*wec[2]  + a0.w*wec[3]
      + a1.x*wec[4]  + a1.y*wec[5]  + a1.z*wec[6]  + a1.w*wec[7]
      + a2.x*wec[8]  + a2.y*wec[9]  + a2.z*wec[10] + a2.w*wec[11]
      + a3.x*wec[12] + a3.y*wec[13] + a3.z*wec[14] + a3.w*wec[15];
    acc += fmaxf(x_in[(size_t)s0 * CC + c] + silu_f(v0), 0.f);
  }
  h_out[(size_t)n * CC + c] = f2bf(x_in[(size_t)n * CC + c] + acc);
}

// ---------------- fused MLP + residual + LayerNorm (MFMA bf16) ----------------

__global__ __launch_bounds__(256) void mlp_kernel(const float* __restrict__ x_in,
                                                  const unsigned short* __restrict__ hbuf,
                                                  const unsigned short* __restrict__ wt1,
                                                  const unsigned short* __restrict__ wt2,
                                                  const float* __restrict__ b1,
                                                  const float* __restrict__ b2,
                                                  const float* __restrict__ gamma,
                                                  const float* __restrict__ beta,
                                                  float* __restrict__ x_out) {
  __shared__ __align__(16) char smem[MTILE * PADC * 2 * 2];  // 43,520 B
  unsigned short* hA = (unsigned short*)smem;                 // [MTILE][PADC]
  unsigned short* tA = (unsigned short*)(smem + MTILE * PADC * 2);
  float* yS = (float*)smem;                                   // [80][YSTR] overlay
  __shared__ float red[MTILE][4][2];

  const int tid = threadIdx.x;
  const int lane = tid & 63;
  const int wv = tid >> 6;
  const int node0 = blockIdx.x * MTILE;
  const int colq = lane & 15;
  const int krow = lane >> 4;
  const int colb = wv * 32;

  for (int idx = tid; idx < MTILE * 16; idx += 256) {
    const int row = idx >> 4, ch = idx & 15;
    *(uint4*)(&hA[row * PADC + ch * 8]) =
        *(const uint4*)(hbuf + (size_t)(node0 + row) * CC + ch * 8);
  }
  __syncthreads();

  bf16x8 bw[2][4];
  #pragma unroll
  for (int n2 = 0; n2 < 2; ++n2)
    #pragma unroll
    for (int kk = 0; kk < 4; ++kk)
      bw[n2][kk] = *(const bf16x8*)(wt1 + (size_t)(colb + n2 * 16 + colq) * CC + kk * 32 + krow * 8);

  f32x4 acc[5][2];
  #pragma unroll
  for (int m = 0; m < 5; ++m) { acc[m][0] = (f32x4)0.f; acc[m][1] = (f32x4)0.f; }

  #pragma unroll
  for (int m = 0; m < 5; ++m)
    #pragma unroll
    for (int kk = 0; kk < 4; ++kk) {
      const bf16x8 a = *(const bf16x8*)(&hA[(m * 16 + colq) * PADC + kk * 32 + krow * 8]);
      acc[m][0] = __builtin_amdgcn_mfma_f32_16x16x32_bf16(a, bw[0][kk], acc[m][0], 0, 0, 0);
      acc[m][1] = __builtin_amdgcn_mfma_f32_16x16x32_bf16(a, bw[1][kk], acc[m][1], 0, 0, 0);
    }

  const float b1v0 = b1[colb + colq], b1v1 = b1[colb + 16 + colq];
  #pragma unroll
  for (int m = 0; m < 5; ++m)
    #pragma unroll
    for (int r = 0; r < 4; ++r) {
      const int row = m * 16 + krow * 4 + r;
      tA[row * PADC + colb + colq]      = f2bf(silu_f(acc[m][0][r] + b1v0));
      tA[row * PADC + colb + 16 + colq] = f2bf(silu_f(acc[m][1][r] + b1v1));
    }
  __syncthreads();

  #pragma unroll
  for (int n2 = 0; n2 < 2; ++n2)
    #pragma unroll
    for (int kk = 0; kk < 4; ++kk)
      bw[n2][kk] = *(const bf16x8*)(wt2 + (size_t)(colb + n2 * 16 + colq) * CC + kk * 32 + krow * 8);

  f32x4 acc2[5][2];
  #pragma unroll
  for (int m = 0; m < 5; ++m) { acc2[m][0] = (f32x4)0.f; acc2[m][1] = (f32x4)0.f; }

  #pragma unroll
  for (int m = 0; m < 5; ++m)
    #pragma unroll
    for (int kk = 0; kk < 4; ++kk) {
      const bf16x8 a = *(const bf16x8*)(&tA[(m * 16 + colq) * PADC + kk * 32 + krow * 8]);
      acc2[m][0] = __builtin_amdgcn_mfma_f32_16x16x32_bf16(a, bw[0][kk], acc2[m][0], 0, 0, 0);
      acc2[m][1] = __builtin_amdgcn_mfma_f32_16x16x32_bf16(a, bw[1][kk], acc2[m][1], 0, 0, 0);
    }

  const float b2v0 = b2[colb + colq], b2v1 = b2[colb + 16 + colq];
  float yv[5][2][4];
  #pragma unroll
  for (int m = 0; m < 5; ++m)
    #pragma unroll
    for (int r = 0; r < 4; ++r) {
      const int row = m * 16 + krow * 4 + r;
      yv[m][0][r] = acc2[m][0][r] + b2v0 + x_in[(size_t)(node0 + row) * CC + colb + colq];
      yv[m][1][r] = acc2[m][1][r] + b2v1 + x_in[(size_t)(node0 + row) * CC + colb + 16 + colq];
    }

  #pragma unroll
  for (int m = 0; m < 5; ++m)
    #pragma unroll
    for (int r = 0; r < 4; ++r) {
      float s = yv[m][0][r] + yv[m][1][r];
      float s2 = yv[m][0][r] * yv[m][0][r] + yv[m][1][r] * yv[m][1][r];
      #pragma unroll
      for (int off = 1; off < 16; off <<= 1) {
        s  += __shfl_xor(s, off);
        s2 += __shfl_xor(s2, off);
      }
      if (colq == 0) {
        const int row = m * 16 + krow * 4 + r;
        red[row][wv][0] = s;
        red[row][wv][1] = s2;
      }
    }
  __syncthreads();

  const float gm0 = gamma[colb + colq], gm1 = gamma[colb + 16 + colq];
  const float bt0 = beta[colb + colq],  bt1 = beta[colb + 16 + colq];
  #pragma unroll
  for (int m = 0; m < 5; ++m)
    #pragma unroll
    for (int r = 0; r < 4; ++r) {
      const int row = m * 16 + krow * 4 + r;
      const float s  = red[row][0][0] + red[row][1][0] + red[row][2][0] + red[row][3][0];
      const float s2 = red[row][0][1] + red[row][1][1] + red[row][2][1] + red[row][3][1];
      const float mean = s * (1.f / 128.f);
      const float var = s2 * (1.f / 128.f) - mean * mean;
      const float rstd = rsqrtf(var + LN_EPS);
      yS[row * YSTR + colb + colq]      = (yv[m][0][r] - mean) * rstd * gm0 + bt0;
      yS[row * YSTR + colb + 16 + colq] = (yv[m][1][r] - mean) * rstd * gm1 + bt1;
    }
  __syncthreads();

  float* og = x_out + (size_t)node0 * CC;
  #pragma unroll
  for (int k = 0; k < 10; ++k) {
    const int u = tid + k * 256;
    const int row = u >> 5, q = u & 31;
    *(float4*)(og + u * 4) = *(const float4*)(&yS[row * YSTR + q * 4]);
  }
}

// ---------------- launch ----------------

extern "C" void kernel_launch(void* const* d_in, const int* in_sizes, int n_in,
                              void* d_out, int out_size, void* d_ws, size_t ws_size,
                              hipStream_t stream) {
  const float* x         = (const float*)d_in[0];
  const float* edge_attr = (const float*)d_in[1];
  const float* We        = (const float*)d_in[2];
  const float* be        = (const float*)d_in[3];
  const float* W1        = (const float*)d_in[4];
  const float* b1        = (const float*)d_in[5];
  const float* W2        = (const float*)d_in[6];
  const float* b2        = (const float*)d_in[7];
  const float* gamma     = (const float*)d_in[8];
  const float* beta      = (const float*)d_in[9];
  const int*   ei        = (const int*)d_in[10];
  const int*   src       = ei;        // edge_index[0]
  const int*   dst       = ei + EE;   // edge_index[1]
  float* out = (float*)d_out;

  char* ws = (char*)d_ws;
  float*          xbuf   = (float*)(ws + 0);                    // 25,600,000
  unsigned short* hbuf   = (unsigned short*)(ws + 25600000);    // 12,800,000 -> 38,400,000
  unsigned short* wt     = (unsigned short*)(ws + 38400000);    //    262,144 -> 38,662,144
  int*            counts = (int*)(ws + 38662400);               //    200,000 -> 38,862,400
  int*            rowptr = (int*)(ws + 38862592);               //    200,004 -> 39,062,596
  int*            cursor = (int*)(ws + 39062784);               //    200,000 -> 39,262,784
  int*            eidx   = (int*)(ws + 39262976);               //  2,400,000 -> 41,662,976
  int*            esrc   = (int*)(ws + 41663232);               //  2,400,000 -> 44,063,232
  float*          attr_csr = (float*)(ws + 44063232);           // 38,400,000 -> 82,463,232
  // webf (8KB) aliases the cursor region -- cursor is dead after fill_kernel.
  unsigned short* webf   = (unsigned short*)(ws + 39062784);
  // scan scratch aliases eidx (dead until fill_kernel, which runs after the scan).
  int*            bsum   = (int*)(ws + 39262976);
  int*            boff   = (int*)(ws + 39262976 + 256);
  const bool use_fast = (ws_size >= 82463232ull);
  const int NB = (NN + 1023) / 1024;   // 49

  hipMemsetAsync(counts, 0, (size_t)NN * 4, stream);
  hipMemsetAsync(cursor, 0, (size_t)NN * 4, stream);
  count_kernel<<<(EE + 255) / 256, 256, 0, stream>>>(dst, counts, EE);
  scan1_kernel<<<NB, 1024, 0, stream>>>(counts, bsum, NN);
  scan2_kernel<<<1, 64, 0, stream>>>(bsum, boff, NB);
  scan3_kernel<<<NB, 1024, 0, stream>>>(counts, boff, rowptr, NN);
  fill_kernel<<<(EE + 255) / 256, 256, 0, stream>>>(src, dst, rowptr, cursor, eidx, esrc, EE);
  wconv_kernel<<<LL * 2 * CC, 128, 0, stream>>>(W1, W2, wt);
  if (use_fast) {
    webconv_kernel<<<16, 256, 0, stream>>>(We, webf);
    gather_attr_kernel<<<(EE * 4 + 255) / 256, 256, 0, stream>>>(edge_attr, eidx, attr_csr);
  }

  const float* xin = x;
  float* bufs[LL] = { xbuf, out, xbuf, out };
  for (int l = 0; l < LL; ++l) {
    float* xo = bufs[l];
    if (use_fast)
      agg5_kernel<<<NN / 4, 256, 0, stream>>>(xin, hbuf, attr_csr, webf, be, rowptr, esrc);
    else
      agg_fb_kernel<<<NN / 2, 256, 0, stream>>>(xin, hbuf, edge_attr, We, be, rowptr, eidx, esrc);
    mlp_kernel<<<NN / MTILE, 256, 0, stream>>>(
        xin, hbuf,
        wt + ((size_t)l * 2) * CC * CC, wt + ((size_t)l * 2 + 1) * CC * CC,
        b1 + (size_t)l * CC, b2 + (size_t)l * CC,
        gamma + (size_t)l * CC, beta + (size_t)l * CC, xo);
    xin = xo;
  }
}

// Round 9
// 540.155 us; speedup vs baseline: 1.2262x; 1.2262x over previous
//
#include <hip/hip_runtime.h>

#define NN 50000
#define EE 600000
#define CC 128
#define ECC 16
#define LL 4
#define LN_EPS 1e-5f
#define MTILE 80
#define PADC 136   // LDS row stride in bf16 elems for hA/tA
#define YSTR 132   // f32 stride for yS overlay (2-way-free banks)

typedef float f32x4 __attribute__((ext_vector_type(4)));
typedef short bf16x8 __attribute__((ext_vector_type(8)));

static __device__ __forceinline__ float bf2f(unsigned short u) {
  union { unsigned int i; float f; } v; v.i = ((unsigned int)u) << 16; return v.f;
}
static __device__ __forceinline__ unsigned short f2bf(float f) {
  union { float f; unsigned int i; } v; v.f = f;
  unsigned int b = v.i + 0x7FFFu + ((v.i >> 16) & 1u);
  return (unsigned short)(b >> 16);
}
static __device__ __forceinline__ float silu_f(float v) {
  return v / (1.f + __expf(-v));
}

// ---------------- CSR build ----------------

__global__ void count_kernel(const int* __restrict__ dst, int* __restrict__ counts, int E) {
  int e = blockIdx.x * blockDim.x + threadIdx.x;
  if (e < E) atomicAdd(&counts[dst[e]], 1);
}

__global__ __launch_bounds__(1024) void scan1_kernel(const int* __restrict__ counts,
                                                     int* __restrict__ bsum, int n) {
  __shared__ int wsum[16];
  const int tid = threadIdx.x, lane = tid & 63, wv = tid >> 6;
  const int i = blockIdx.x * 1024 + tid;
  int s = (i < n) ? counts[i] : 0;
  #pragma unroll
  for (int off = 1; off < 64; off <<= 1) s += __shfl_xor(s, off);
  if (lane == 0) wsum[wv] = s;
  __syncthreads();
  if (tid == 0) {
    int t = 0;
    #pragma unroll
    for (int j = 0; j < 16; ++j) t += wsum[j];
    bsum[blockIdx.x] = t;
  }
}

__global__ void scan2_kernel(const int* __restrict__ bsum, int* __restrict__ boff, int nb) {
  const int lane = threadIdx.x;   // one wave
  int v = (lane < nb) ? bsum[lane] : 0;
  int incl = v;
  #pragma unroll
  for (int off = 1; off < 64; off <<= 1) {
    int t = __shfl_up(incl, off);
    if (lane >= off) incl += t;
  }
  if (lane < nb) boff[lane] = incl - v;
}

__global__ __launch_bounds__(1024) void scan3_kernel(const int* __restrict__ counts,
                                                     const int* __restrict__ boff,
                                                     int* __restrict__ rowptr, int n) {
  __shared__ int wsum[16];
  const int tid = threadIdx.x, lane = tid & 63, wv = tid >> 6;
  const int i = blockIdx.x * 1024 + tid;
  const int v = (i < n) ? counts[i] : 0;
  int incl = v;
  #pragma unroll
  for (int off = 1; off < 64; off <<= 1) {
    int t = __shfl_up(incl, off);
    if (lane >= off) incl += t;
  }
  if (lane == 63) wsum[wv] = incl;
  __syncthreads();
  if (wv == 0) {
    int vv = (lane < 16) ? wsum[lane] : 0;
    int vi = vv;
    #pragma unroll
    for (int off = 1; off < 16; off <<= 1) {
      int t = __shfl_up(vi, off);
      if (lane >= off) vi += t;
    }
    if (lane < 16) wsum[lane] = vi - vv;   // exclusive wave prefix
  }
  __syncthreads();
  if (i < n) rowptr[i + 1] = boff[blockIdx.x] + wsum[wv] + incl;
  if (i == 0) rowptr[0] = 0;
}

__global__ void fill_kernel(const int* __restrict__ src, const int* __restrict__ dst,
                            const int* __restrict__ rowptr, int* __restrict__ cursor,
                            int* __restrict__ eidx, int* __restrict__ esrc, int E) {
  int e = blockIdx.x * blockDim.x + threadIdx.x;
  if (e < E) {
    const int d = dst[e];
    const int pos = rowptr[d] + atomicAdd(&cursor[d], 1);
    eidx[pos] = e;
    esrc[pos] = src[e];
  }
}

// ---------------- We B-fragment prep (bf16, MFMA fragment order) ----------------

__global__ void webconv_kernel(const float* __restrict__ We, unsigned short* __restrict__ webf) {
  const int t = blockIdx.x * blockDim.x + threadIdx.x;
  if (t >= 8 * 64 * 8) return;
  const int j = t & 7, l = (t >> 3) & 63, cg = t >> 9;
  const int k = (l >> 4) * 8 + j, c = cg * 16 + (l & 15);
  webf[t] = (k < 16) ? f2bf(We[k * CC + c]) : (unsigned short)0;
}

// ---------------- ea precompute via MFMA (CSR order, bf16, coalesced stores) ----------------

__global__ __launch_bounds__(256) void ea_kernel(const float* __restrict__ edge_attr,
                                                 const unsigned short* __restrict__ webf,
                                                 const float* __restrict__ be,
                                                 const int* __restrict__ eidx,
                                                 unsigned short* __restrict__ ea) {
  __shared__ float er[64][20];             // pad 20: 16B-aligned float4 rows
  __shared__ unsigned short eaT[64 * 132]; // repack tile, stride 132 shorts (264B)
  const int tid = threadIdx.x;
  const int lane = tid & 63, wv = tid >> 6;

  bf16x8 bw[8];
  #pragma unroll
  for (int cg = 0; cg < 8; ++cg)
    bw[cg] = *(const bf16x8*)(webf + cg * 512 + lane * 8);
  float bev[8];
  #pragma unroll
  for (int cg = 0; cg < 8; ++cg) bev[cg] = be[cg * 16 + (lane & 15)];

  const int base = blockIdx.x * 64;
  {
    const int r = tid >> 2, q = tid & 3;
    const int e = eidx[base + r];
    *(float4*)(&er[r][q * 4]) = *(const float4*)(edge_attr + (size_t)e * ECC + q * 4);
  }
  __syncthreads();

  const int arow = wv * 16 + (lane & 15);
  const int ko = lane >> 4;
  union { unsigned short u[8]; bf16x8 v; } afu;
  if (ko < 2) {
    #pragma unroll
    for (int j = 0; j < 8; ++j) afu.u[j] = f2bf(er[arow][ko * 8 + j]);
  } else {
    #pragma unroll
    for (int j = 0; j < 8; ++j) afu.u[j] = 0;
  }

  f32x4 acc[8];
  #pragma unroll
  for (int cg = 0; cg < 8; ++cg) {
    acc[cg] = (f32x4)0.f;
    acc[cg] = __builtin_amdgcn_mfma_f32_16x16x32_bf16(afu.v, bw[cg], acc[cg], 0, 0, 0);
  }

  const int rl0 = wv * 16 + ko * 4;
  const int cb = lane & 15;
  #pragma unroll
  for (int cg = 0; cg < 8; ++cg)
    #pragma unroll
    for (int r = 0; r < 4; ++r) {
      const float v = acc[cg][r] + bev[cg];
      eaT[(rl0 + r) * 132 + cg * 16 + cb] = f2bf(silu_f(v));
    }
  __syncthreads();

  uint4* eg = (uint4*)(ea + (size_t)base * CC);
  #pragma unroll
  for (int k = 0; k < 4; ++k) {
    const int u = tid + k * 256;
    const int row = u >> 4, ch = u & 15;
    eg[u] = *(const uint4*)(&eaT[row * 132 + ch * 8]);
  }
}

// ---------------- weight transpose+cast: wt[l][mat][c][k] = bf16(W[l][k][c]) ----------------

__global__ __launch_bounds__(128) void wconv_kernel(const float* __restrict__ W1,
                                                    const float* __restrict__ W2,
                                                    unsigned short* __restrict__ wt) {
  const int b = blockIdx.x;
  const int c = b & (CC - 1);
  const int mat = (b >> 7) & 1;
  const int l = b >> 8;
  const float* W = (mat ? W2 : W1) + (size_t)l * CC * CC;
  unsigned short* o = wt + ((size_t)l * 2 + mat) * CC * CC + (size_t)c * CC;
  const int k = threadIdx.x;
  o[k] = f2bf(W[(size_t)k * CC + c]);
}

// ---------------- aggregation: half-wave per edge, 4 channels/lane, x4 unroll ----------------

__global__ __launch_bounds__(256) void agg4_kernel(const float* __restrict__ x_in,
                                                   unsigned short* __restrict__ h_out,
                                                   const unsigned short* __restrict__ ea,
                                                   const int* __restrict__ rowptr,
                                                   const int* __restrict__ esrc) {
  const int tid = threadIdx.x;
  const int lane = tid & 63;
  const int half = lane >> 5;
  const int l32 = lane & 31;
  const int c0 = l32 * 4;
  const int wv = tid >> 6;
  const int n = blockIdx.x * 4 + wv;

  const int p0 = rowptr[n], p1 = rowptr[n + 1];
  float a0 = 0.f, a1 = 0.f, a2 = 0.f, a3 = 0.f;

  int p = p0 + half;   // this half's positions: stride 2
  // 4 edges per iteration per half -> 8 loads in flight per lane
  for (; p + 6 < p1; p += 8) {
    const int s0 = esrc[p], s1 = esrc[p + 2], s2 = esrc[p + 4], s3 = esrc[p + 6];
    const float4 x0 = *(const float4*)(x_in + (size_t)s0 * CC + c0);
    const float4 x1 = *(const float4*)(x_in + (size_t)s1 * CC + c0);
    const float4 x2 = *(const float4*)(x_in + (size_t)s2 * CC + c0);
    const float4 x3 = *(const float4*)(x_in + (size_t)s3 * CC + c0);
    const uint2 e0 = *(const uint2*)(ea + (size_t)p * CC + c0);
    const uint2 e1 = *(const uint2*)(ea + (size_t)(p + 2) * CC + c0);
    const uint2 e2 = *(const uint2*)(ea + (size_t)(p + 4) * CC + c0);
    const uint2 e3 = *(const uint2*)(ea + (size_t)(p + 6) * CC + c0);
    a0 += fmaxf(x0.x + bf2f((unsigned short)e0.x), 0.f)
        + fmaxf(x1.x + bf2f((unsigned short)e1.x), 0.f)
        + fmaxf(x2.x + bf2f((unsigned short)e2.x), 0.f)
        + fmaxf(x3.x + bf2f((unsigned short)e3.x), 0.f);
    a1 += fmaxf(x0.y + bf2f((unsigned short)(e0.x >> 16)), 0.f)
        + fmaxf(x1.y + bf2f((unsigned short)(e1.x >> 16)), 0.f)
        + fmaxf(x2.y + bf2f((unsigned short)(e2.x >> 16)), 0.f)
        + fmaxf(x3.y + bf2f((unsigned short)(e3.x >> 16)), 0.f);
    a2 += fmaxf(x0.z + bf2f((unsigned short)e0.y), 0.f)
        + fmaxf(x1.z + bf2f((unsigned short)e1.y), 0.f)
        + fmaxf(x2.z + bf2f((unsigned short)e2.y), 0.f)
        + fmaxf(x3.z + bf2f((unsigned short)e3.y), 0.f);
    a3 += fmaxf(x0.w + bf2f((unsigned short)(e0.y >> 16)), 0.f)
        + fmaxf(x1.w + bf2f((unsigned short)(e1.y >> 16)), 0.f)
        + fmaxf(x2.w + bf2f((unsigned short)(e2.y >> 16)), 0.f)
        + fmaxf(x3.w + bf2f((unsigned short)(e3.y >> 16)), 0.f);
  }
  for (; p + 2 < p1; p += 4) {
    const int s0 = esrc[p], s1 = esrc[p + 2];
    const float4 x0 = *(const float4*)(x_in + (size_t)s0 * CC + c0);
    const float4 x1 = *(const float4*)(x_in + (size_t)s1 * CC + c0);
    const uint2 e0 = *(const uint2*)(ea + (size_t)p * CC + c0);
    const uint2 e1 = *(const uint2*)(ea + (size_t)(p + 2) * CC + c0);
    a0 += fmaxf(x0.x + bf2f((unsigned short)e0.x), 0.f)
        + fmaxf(x1.x + bf2f((unsigned short)e1.x), 0.f);
    a1 += fmaxf(x0.y + bf2f((unsigned short)(e0.x >> 16)), 0.f)
        + fmaxf(x1.y + bf2f((unsigned short)(e1.x >> 16)), 0.f);
    a2 += fmaxf(x0.z + bf2f((unsigned short)e0.y), 0.f)
        + fmaxf(x1.z + bf2f((unsigned short)e1.y), 0.f);
    a3 += fmaxf(x0.w + bf2f((unsigned short)(e0.y >> 16)), 0.f)
        + fmaxf(x1.w + bf2f((unsigned short)(e1.y >> 16)), 0.f);
  }
  if (p < p1) {
    const int s0 = esrc[p];
    const float4 x0 = *(const float4*)(x_in + (size_t)s0 * CC + c0);
    const uint2 e0 = *(const uint2*)(ea + (size_t)p * CC + c0);
    a0 += fmaxf(x0.x + bf2f((unsigned short)e0.x), 0.f);
    a1 += fmaxf(x0.y + bf2f((unsigned short)(e0.x >> 16)), 0.f);
    a2 += fmaxf(x0.z + bf2f((unsigned short)e0.y), 0.f);
    a3 += fmaxf(x0.w + bf2f((unsigned short)(e0.y >> 16)), 0.f);
  }

  a0 += __shfl_xor(a0, 32);
  a1 += __shfl_xor(a1, 32);
  a2 += __shfl_xor(a2, 32);
  a3 += __shfl_xor(a3, 32);

  if (half == 0) {
    const float4 xs = *(const float4*)(x_in + (size_t)n * CC + c0);
    uint2 pk;
    pk.x = (unsigned int)f2bf(xs.x + a0) | ((unsigned int)f2bf(xs.y + a1) << 16);
    pk.y = (unsigned int)f2bf(xs.z + a2) | ((unsigned int)f2bf(xs.w + a3) << 16);
    *(uint2*)(h_out + (size_t)n * CC + c0) = pk;
  }
}

// ---------------- aggregation (fallback: small ws, recompute via eidx) ----------------

__global__ __launch_bounds__(256) void agg_fb_kernel(const float* __restrict__ x_in,
                                                     unsigned short* __restrict__ h_out,
                                                     const float* __restrict__ edge_attr,
                                                     const float* __restrict__ We,
                                                     const float* __restrict__ be,
                                                     const int* __restrict__ rowptr,
                                                     const int* __restrict__ eidx,
                                                     const int* __restrict__ esrc) {
  const int tid = threadIdx.x;
  const int c = tid & (CC - 1);
  const int g = tid >> 7;
  const int n = blockIdx.x * 2 + g;

  float wec[ECC];
  #pragma unroll
  for (int k = 0; k < ECC; ++k) wec[k] = We[k * CC + c];
  const float bev = be[c];

  const int p0 = rowptr[n], p1 = rowptr[n + 1];
  float acc = 0.f;
  for (int p = p0; p < p1; ++p) {
    const int e0 = eidx[p];
    const int s0 = esrc[p];
    const float4* ar0 = (const float4*)(edge_attr + (size_t)e0 * ECC);
    const float4 a0 = ar0[0], a1 = ar0[1], a2 = ar0[2], a3 = ar0[3];
    float v0 = bev
      + a0.x*wec[0]  + a0.y*wec[1]  + a0.z*wec[2]  + a0.w*wec[3]
      + a1.x*wec[4]  + a1.y*wec[5]  + a1.z*wec[6]  + a1.w*wec[7]
      + a2.x*wec[8]  + a2.y*wec[9]  + a2.z*wec[10] + a2.w*wec[11]
      + a3.x*wec[12] + a3.y*wec[13] + a3.z*wec[14] + a3.w*wec[15];
    acc += fmaxf(x_in[(size_t)s0 * CC + c] + silu_f(v0), 0.f);
  }
  h_out[(size_t)n * CC + c] = f2bf(x_in[(size_t)n * CC + c] + acc);
}

// ---------------- fused MLP + residual + LayerNorm (MFMA bf16, 8 waves) ----------------
// Block: 512 threads (8 waves), MTILE=80 nodes. Wave w owns output cols [16w, 16w+16).
// Weight fragments for BOTH GEMMs preloaded to registers before hA staging
// (global-load latency hidden under the staging loop).

__global__ __launch_bounds__(512) void mlp_kernel(const float* __restrict__ x_in,
                                                  const unsigned short* __restrict__ hbuf,
                                                  const unsigned short* __restrict__ wt1,
                                                  const unsigned short* __restrict__ wt2,
                                                  const float* __restrict__ b1,
                                                  const float* __restrict__ b2,
                                                  const float* __restrict__ gamma,
                                                  const float* __restrict__ beta,
                                                  float* __restrict__ x_out) {
  __shared__ __align__(16) char smem[MTILE * PADC * 2 * 2];  // 43,520 B
  unsigned short* hA = (unsigned short*)smem;                 // [MTILE][PADC]
  unsigned short* tA = (unsigned short*)(smem + MTILE * PADC * 2);
  float* yS = (float*)smem;                                   // [80][YSTR] overlay
  __shared__ float red[MTILE][8][2];                          // 5,120 B

  const int tid = threadIdx.x;
  const int lane = tid & 63;
  const int wv = tid >> 6;            // 0..7
  const int node0 = blockIdx.x * MTILE;
  const int colq = lane & 15;
  const int krow = lane >> 4;
  const int colb = wv * 16;

  // preload both GEMMs' weight fragments (issued before staging -> latency hidden)
  bf16x8 bw1[4], bw2[4];
  #pragma unroll
  for (int kk = 0; kk < 4; ++kk) {
    bw1[kk] = *(const bf16x8*)(wt1 + (size_t)(colb + colq) * CC + kk * 32 + krow * 8);
    bw2[kk] = *(const bf16x8*)(wt2 + (size_t)(colb + colq) * CC + kk * 32 + krow * 8);
  }

  // stage h tile: 80 rows x 256B = 1280 uint4 units
  for (int idx = tid; idx < MTILE * 16; idx += 512) {
    const int row = idx >> 4, ch = idx & 15;
    *(uint4*)(&hA[row * PADC + ch * 8]) =
        *(const uint4*)(hbuf + (size_t)(node0 + row) * CC + ch * 8);
  }
  __syncthreads();

  // ---- GEMM1: t = silu(h @ W1 + b1) ----
  f32x4 acc[5];
  #pragma unroll
  for (int m = 0; m < 5; ++m) acc[m] = (f32x4)0.f;
  #pragma unroll
  for (int m = 0; m < 5; ++m)
    #pragma unroll
    for (int kk = 0; kk < 4; ++kk) {
      const bf16x8 a = *(const bf16x8*)(&hA[(m * 16 + colq) * PADC + kk * 32 + krow * 8]);
      acc[m] = __builtin_amdgcn_mfma_f32_16x16x32_bf16(a, bw1[kk], acc[m], 0, 0, 0);
    }

  const float b1v = b1[colb + colq];
  #pragma unroll
  for (int m = 0; m < 5; ++m)
    #pragma unroll
    for (int r = 0; r < 4; ++r) {
      const int row = m * 16 + krow * 4 + r;
      tA[row * PADC + colb + colq] = f2bf(silu_f(acc[m][r] + b1v));
    }
  __syncthreads();

  // ---- GEMM2: y = x + t @ W2 + b2 ----
  f32x4 acc2[5];
  #pragma unroll
  for (int m = 0; m < 5; ++m) acc2[m] = (f32x4)0.f;
  #pragma unroll
  for (int m = 0; m < 5; ++m)
    #pragma unroll
    for (int kk = 0; kk < 4; ++kk) {
      const bf16x8 a = *(const bf16x8*)(&tA[(m * 16 + colq) * PADC + kk * 32 + krow * 8]);
      acc2[m] = __builtin_amdgcn_mfma_f32_16x16x32_bf16(a, bw2[kk], acc2[m], 0, 0, 0);
    }

  const float b2v = b2[colb + colq];
  float yv[5][4];
  #pragma unroll
  for (int m = 0; m < 5; ++m)
    #pragma unroll
    for (int r = 0; r < 4; ++r) {
      const int row = m * 16 + krow * 4 + r;
      yv[m][r] = acc2[m][r] + b2v + x_in[(size_t)(node0 + row) * CC + colb + colq];
    }

  // ---- LayerNorm: per-row stats across 8 waves ----
  #pragma unroll
  for (int m = 0; m < 5; ++m)
    #pragma unroll
    for (int r = 0; r < 4; ++r) {
      float s = yv[m][r];
      float s2 = yv[m][r] * yv[m][r];
      #pragma unroll
      for (int off = 1; off < 16; off <<= 1) {
        s  += __shfl_xor(s, off);
        s2 += __shfl_xor(s2, off);
      }
      if (colq == 0) {
        const int row = m * 16 + krow * 4 + r;
        red[row][wv][0] = s;
        red[row][wv][1] = s2;
      }
    }
  __syncthreads();   // red ready; also orders all tA reads before yS overlay writes

  const float gm = gamma[colb + colq];
  const float bt = beta[colb + colq];
  #pragma unroll
  for (int m = 0; m < 5; ++m)
    #pragma unroll
    for (int r = 0; r < 4; ++r) {
      const int row = m * 16 + krow * 4 + r;
      float s = 0.f, s2 = 0.f;
      #pragma unroll
      for (int w = 0; w < 8; ++w) { s += red[row][w][0]; s2 += red[row][w][1]; }
      const float mean = s * (1.f / 128.f);
      const float var = s2 * (1.f / 128.f) - mean * mean;
      const float rstd = rsqrtf(var + LN_EPS);
      yS[row * YSTR + colb + colq] = (yv[m][r] - mean) * rstd * gm + bt;
    }
  __syncthreads();

  // coalesced store: 80 rows x 512B = 2560 units of 16B
  float* og = x_out + (size_t)node0 * CC;
  #pragma unroll
  for (int k = 0; k < 5; ++k) {
    const int u = tid + k * 512;
    const int row = u >> 5, q = u & 31;
    *(float4*)(og + u * 4) = *(const float4*)(&yS[row * YSTR + q * 4]);
  }
}

// ---------------- launch ----------------

extern "C" void kernel_launch(void* const* d_in, const int* in_sizes, int n_in,
                              void* d_out, int out_size, void* d_ws, size_t ws_size,
                              hipStream_t stream) {
  const float* x         = (const float*)d_in[0];
  const float* edge_attr = (const float*)d_in[1];
  const float* We        = (const float*)d_in[2];
  const float* be        = (const float*)d_in[3];
  const float* W1        = (const float*)d_in[4];
  const float* b1        = (const float*)d_in[5];
  const float* W2        = (const float*)d_in[6];
  const float* b2        = (const float*)d_in[7];
  const float* gamma     = (const float*)d_in[8];
  const float* beta      = (const float*)d_in[9];
  const int*   ei        = (const int*)d_in[10];
  const int*   src       = ei;        // edge_index[0]
  const int*   dst       = ei + EE;   // edge_index[1]
  float* out = (float*)d_out;

  char* ws = (char*)d_ws;
  float*          xbuf   = (float*)(ws + 0);                    // 25,600,000
  unsigned short* hbuf   = (unsigned short*)(ws + 25600000);    // 12,800,000 -> 38,400,000
  unsigned short* wt     = (unsigned short*)(ws + 38400000);    //    262,144 -> 38,662,144
  int*            counts = (int*)(ws + 38662400);               //    200,000 -> 38,862,400
  int*            rowptr = (int*)(ws + 38862592);               //    200,004 -> 39,062,596
  int*            cursor = (int*)(ws + 39062784);               //    200,000 -> 39,262,784
  int*            eidx   = (int*)(ws + 39262976);               //  2,400,000 -> 41,662,976
  int*            esrc   = (int*)(ws + 41663232);               //  2,400,000 -> 44,063,232
  unsigned short* ea     = (unsigned short*)(ws + 44063232);    // 153,600,000 -> 197,663,232
  // webf (8KB) aliases the cursor region -- cursor is dead after fill_kernel.
  unsigned short* webf   = (unsigned short*)(ws + 39062784);
  // scan scratch aliases eidx (dead until fill_kernel, which runs after the scan).
  int*            bsum   = (int*)(ws + 39262976);
  int*            boff   = (int*)(ws + 39262976 + 256);
  const bool use_ea = (ws_size >= 197663232ull);
  const int NB = (NN + 1023) / 1024;   // 49

  hipMemsetAsync(counts, 0, (size_t)NN * 4, stream);
  hipMemsetAsync(cursor, 0, (size_t)NN * 4, stream);
  count_kernel<<<(EE + 255) / 256, 256, 0, stream>>>(dst, counts, EE);
  scan1_kernel<<<NB, 1024, 0, stream>>>(counts, bsum, NN);
  scan2_kernel<<<1, 64, 0, stream>>>(bsum, boff, NB);
  scan3_kernel<<<NB, 1024, 0, stream>>>(counts, boff, rowptr, NN);
  fill_kernel<<<(EE + 255) / 256, 256, 0, stream>>>(src, dst, rowptr, cursor, eidx, esrc, EE);
  wconv_kernel<<<LL * 2 * CC, 128, 0, stream>>>(W1, W2, wt);
  if (use_ea) {
    webconv_kernel<<<16, 256, 0, stream>>>(We, webf);
    ea_kernel<<<EE / 64, 256, 0, stream>>>(edge_attr, webf, be, eidx, ea);
  }

  const float* xin = x;
  float* bufs[LL] = { xbuf, out, xbuf, out };
  for (int l = 0; l < LL; ++l) {
    float* xo = bufs[l];
    if (use_ea)
      agg4_kernel<<<NN / 4, 256, 0, stream>>>(xin, hbuf, ea, rowptr, esrc);
    else
      agg_fb_kernel<<<NN / 2, 256, 0, stream>>>(xin, hbuf, edge_attr, We, be, rowptr, eidx, esrc);
    mlp_kernel<<<NN / MTILE, 512, 0, stream>>>(
        xin, hbuf,
        wt + ((size_t)l * 2) * CC * CC, wt + ((size_t)l * 2 + 1) * CC * CC,
        b1 + (size_t)l * CC, b2 + (size_t)l * CC,
        gamma + (size_t)l * CC, beta + (size_t)l * CC, xo);
    xin = xo;
  }
}

// Round 10
// 415.909 us; speedup vs baseline: 1.5925x; 1.2987x over previous
//
#include <hip/hip_runtime.h>

#define NN 50000
#define EE 600000
#define CC 128
#define ECC 16
#define LL 4
#define LN_EPS 1e-5f
#define MTILE 80
#define PADC 136   // LDS row stride in bf16 elems for hA/tA
#define YSTR 132   // f32 stride for yS overlay (2-way-free banks)

typedef float f32x4 __attribute__((ext_vector_type(4)));
typedef short bf16x8 __attribute__((ext_vector_type(8)));

static __device__ __forceinline__ float bf2f(unsigned short u) {
  union { unsigned int i; float f; } v; v.i = ((unsigned int)u) << 16; return v.f;
}
static __device__ __forceinline__ unsigned short f2bf(float f) {
  union { float f; unsigned int i; } v; v.f = f;
  unsigned int b = v.i + 0x7FFFu + ((v.i >> 16) & 1u);
  return (unsigned short)(b >> 16);
}
static __device__ __forceinline__ float silu_f(float v) {
  return v / (1.f + __expf(-v));
}

// ---------------- CSR build ----------------

__global__ void count_kernel(const int* __restrict__ dst, int* __restrict__ counts, int E) {
  int e = blockIdx.x * blockDim.x + threadIdx.x;
  if (e < E) atomicAdd(&counts[dst[e]], 1);
}

__global__ __launch_bounds__(1024) void scan1_kernel(const int* __restrict__ counts,
                                                     int* __restrict__ bsum, int n) {
  __shared__ int wsum[16];
  const int tid = threadIdx.x, lane = tid & 63, wv = tid >> 6;
  const int i = blockIdx.x * 1024 + tid;
  int s = (i < n) ? counts[i] : 0;
  #pragma unroll
  for (int off = 1; off < 64; off <<= 1) s += __shfl_xor(s, off);
  if (lane == 0) wsum[wv] = s;
  __syncthreads();
  if (tid == 0) {
    int t = 0;
    #pragma unroll
    for (int j = 0; j < 16; ++j) t += wsum[j];
    bsum[blockIdx.x] = t;
  }
}

__global__ void scan2_kernel(const int* __restrict__ bsum, int* __restrict__ boff, int nb) {
  const int lane = threadIdx.x;   // one wave
  int v = (lane < nb) ? bsum[lane] : 0;
  int incl = v;
  #pragma unroll
  for (int off = 1; off < 64; off <<= 1) {
    int t = __shfl_up(incl, off);
    if (lane >= off) incl += t;
  }
  if (lane < nb) boff[lane] = incl - v;
}

__global__ __launch_bounds__(1024) void scan3_kernel(const int* __restrict__ counts,
                                                     const int* __restrict__ boff,
                                                     int* __restrict__ rowptr, int n) {
  __shared__ int wsum[16];
  const int tid = threadIdx.x, lane = tid & 63, wv = tid >> 6;
  const int i = blockIdx.x * 1024 + tid;
  const int v = (i < n) ? counts[i] : 0;
  int incl = v;
  #pragma unroll
  for (int off = 1; off < 64; off <<= 1) {
    int t = __shfl_up(incl, off);
    if (lane >= off) incl += t;
  }
  if (lane == 63) wsum[wv] = incl;
  __syncthreads();
  if (wv == 0) {
    int vv = (lane < 16) ? wsum[lane] : 0;
    int vi = vv;
    #pragma unroll
    for (int off = 1; off < 16; off <<= 1) {
      int t = __shfl_up(vi, off);
      if (lane >= off) vi += t;
    }
    if (lane < 16) wsum[lane] = vi - vv;   // exclusive wave prefix
  }
  __syncthreads();
  if (i < n) rowptr[i + 1] = boff[blockIdx.x] + wsum[wv] + incl;
  if (i == 0) rowptr[0] = 0;
}

__global__ void fill_kernel(const int* __restrict__ src, const int* __restrict__ dst,
                            const int* __restrict__ rowptr, int* __restrict__ cursor,
                            int* __restrict__ eidx, int* __restrict__ esrc, int E) {
  int e = blockIdx.x * blockDim.x + threadIdx.x;
  if (e < E) {
    const int d = dst[e];
    const int pos = rowptr[d] + atomicAdd(&cursor[d], 1);
    eidx[pos] = e;
    esrc[pos] = src[e];
  }
}

// ---------------- x f32 -> bf16 conversion (once) ----------------

__global__ __launch_bounds__(256) void xconv_kernel(const float* __restrict__ x,
                                                    unsigned short* __restrict__ xb) {
  const int t = blockIdx.x * 256 + threadIdx.x;   // 8 elems each
  if (t >= NN * CC / 8) return;
  const float4 a = ((const float4*)x)[t * 2];
  const float4 b = ((const float4*)x)[t * 2 + 1];
  uint4 o;
  o.x = (unsigned)f2bf(a.x) | ((unsigned)f2bf(a.y) << 16);
  o.y = (unsigned)f2bf(a.z) | ((unsigned)f2bf(a.w) << 16);
  o.z = (unsigned)f2bf(b.x) | ((unsigned)f2bf(b.y) << 16);
  o.w = (unsigned)f2bf(b.z) | ((unsigned)f2bf(b.w) << 16);
  ((uint4*)xb)[t] = o;
}

// ---------------- We B-fragment prep (bf16, MFMA fragment order) ----------------

__global__ void webconv_kernel(const float* __restrict__ We, unsigned short* __restrict__ webf) {
  const int t = blockIdx.x * blockDim.x + threadIdx.x;
  if (t >= 8 * 64 * 8) return;
  const int j = t & 7, l = (t >> 3) & 63, cg = t >> 9;
  const int k = (l >> 4) * 8 + j, c = cg * 16 + (l & 15);
  webf[t] = (k < 16) ? f2bf(We[k * CC + c]) : (unsigned short)0;
}

// ---------------- ea precompute via MFMA (CSR order, bf16, coalesced stores) ----------------

__global__ __launch_bounds__(256) void ea_kernel(const float* __restrict__ edge_attr,
                                                 const unsigned short* __restrict__ webf,
                                                 const float* __restrict__ be,
                                                 const int* __restrict__ eidx,
                                                 unsigned short* __restrict__ ea) {
  __shared__ float er[64][20];             // pad 20: 16B-aligned float4 rows
  __shared__ unsigned short eaT[64 * 132]; // repack tile, stride 132 shorts
  const int tid = threadIdx.x;
  const int lane = tid & 63, wv = tid >> 6;

  bf16x8 bw[8];
  #pragma unroll
  for (int cg = 0; cg < 8; ++cg)
    bw[cg] = *(const bf16x8*)(webf + cg * 512 + lane * 8);
  float bev[8];
  #pragma unroll
  for (int cg = 0; cg < 8; ++cg) bev[cg] = be[cg * 16 + (lane & 15)];

  const int base = blockIdx.x * 64;
  {
    const int r = tid >> 2, q = tid & 3;
    const int e = eidx[base + r];
    *(float4*)(&er[r][q * 4]) = *(const float4*)(edge_attr + (size_t)e * ECC + q * 4);
  }
  __syncthreads();

  const int arow = wv * 16 + (lane & 15);
  const int ko = lane >> 4;
  union { unsigned short u[8]; bf16x8 v; } afu;
  if (ko < 2) {
    #pragma unroll
    for (int j = 0; j < 8; ++j) afu.u[j] = f2bf(er[arow][ko * 8 + j]);
  } else {
    #pragma unroll
    for (int j = 0; j < 8; ++j) afu.u[j] = 0;
  }

  f32x4 acc[8];
  #pragma unroll
  for (int cg = 0; cg < 8; ++cg) {
    acc[cg] = (f32x4)0.f;
    acc[cg] = __builtin_amdgcn_mfma_f32_16x16x32_bf16(afu.v, bw[cg], acc[cg], 0, 0, 0);
  }

  const int rl0 = wv * 16 + ko * 4;
  const int cb = lane & 15;
  #pragma unroll
  for (int cg = 0; cg < 8; ++cg)
    #pragma unroll
    for (int r = 0; r < 4; ++r) {
      const float v = acc[cg][r] + bev[cg];
      eaT[(rl0 + r) * 132 + cg * 16 + cb] = f2bf(silu_f(v));
    }
  __syncthreads();

  uint4* eg = (uint4*)(ea + (size_t)base * CC);
  #pragma unroll
  for (int k = 0; k < 4; ++k) {
    const int u = tid + k * 256;
    const int row = u >> 4, ch = u & 15;
    eg[u] = *(const uint4*)(&eaT[row * 132 + ch * 8]);
  }
}

// ---------------- weight transpose+cast: wt[l][mat][c][k] = bf16(W[l][k][c]) ----------------

__global__ __launch_bounds__(128) void wconv_kernel(const float* __restrict__ W1,
                                                    const float* __restrict__ W2,
                                                    unsigned short* __restrict__ wt) {
  const int b = blockIdx.x;
  const int c = b & (CC - 1);
  const int mat = (b >> 7) & 1;
  const int l = b >> 8;
  const float* W = (mat ? W2 : W1) + (size_t)l * CC * CC;
  unsigned short* o = wt + ((size_t)l * 2 + mat) * CC * CC + (size_t)c * CC;
  const int k = threadIdx.x;
  o[k] = f2bf(W[(size_t)k * CC + c]);
}

// ---------------- aggregation: half-wave per edge, 4 bf16 channels/lane ----------------
// x gathered as bf16 (8B/lane, 256B/edge-row) -- halves the gather traffic.

__global__ __launch_bounds__(256) void agg4_kernel(const unsigned short* __restrict__ xb,
                                                   unsigned short* __restrict__ h_out,
                                                   const unsigned short* __restrict__ ea,
                                                   const int* __restrict__ rowptr,
                                                   const int* __restrict__ esrc) {
  const int tid = threadIdx.x;
  const int lane = tid & 63;
  const int half = lane >> 5;
  const int l32 = lane & 31;
  const int c0 = l32 * 4;
  const int wv = tid >> 6;
  const int n = blockIdx.x * 4 + wv;

  const int p0 = rowptr[n], p1 = rowptr[n + 1];
  float a0 = 0.f, a1 = 0.f, a2 = 0.f, a3 = 0.f;

  int p = p0 + half;
  for (; p + 6 < p1; p += 8) {
    const int s0 = esrc[p], s1 = esrc[p + 2], s2 = esrc[p + 4], s3 = esrc[p + 6];
    const uint2 x0 = *(const uint2*)(xb + (size_t)s0 * CC + c0);
    const uint2 x1 = *(const uint2*)(xb + (size_t)s1 * CC + c0);
    const uint2 x2 = *(const uint2*)(xb + (size_t)s2 * CC + c0);
    const uint2 x3 = *(const uint2*)(xb + (size_t)s3 * CC + c0);
    const uint2 e0 = *(const uint2*)(ea + (size_t)p * CC + c0);
    const uint2 e1 = *(const uint2*)(ea + (size_t)(p + 2) * CC + c0);
    const uint2 e2 = *(const uint2*)(ea + (size_t)(p + 4) * CC + c0);
    const uint2 e3 = *(const uint2*)(ea + (size_t)(p + 6) * CC + c0);
    a0 += fmaxf(bf2f((unsigned short)x0.x) + bf2f((unsigned short)e0.x), 0.f)
        + fmaxf(bf2f((unsigned short)x1.x) + bf2f((unsigned short)e1.x), 0.f)
        + fmaxf(bf2f((unsigned short)x2.x) + bf2f((unsigned short)e2.x), 0.f)
        + fmaxf(bf2f((unsigned short)x3.x) + bf2f((unsigned short)e3.x), 0.f);
    a1 += fmaxf(bf2f((unsigned short)(x0.x >> 16)) + bf2f((unsigned short)(e0.x >> 16)), 0.f)
        + fmaxf(bf2f((unsigned short)(x1.x >> 16)) + bf2f((unsigned short)(e1.x >> 16)), 0.f)
        + fmaxf(bf2f((unsigned short)(x2.x >> 16)) + bf2f((unsigned short)(e2.x >> 16)), 0.f)
        + fmaxf(bf2f((unsigned short)(x3.x >> 16)) + bf2f((unsigned short)(e3.x >> 16)), 0.f);
    a2 += fmaxf(bf2f((unsigned short)x0.y) + bf2f((unsigned short)e0.y), 0.f)
        + fmaxf(bf2f((unsigned short)x1.y) + bf2f((unsigned short)e1.y), 0.f)
        + fmaxf(bf2f((unsigned short)x2.y) + bf2f((unsigned short)e2.y), 0.f)
        + fmaxf(bf2f((unsigned short)x3.y) + bf2f((unsigned short)e3.y), 0.f);
    a3 += fmaxf(bf2f((unsigned short)(x0.y >> 16)) + bf2f((unsigned short)(e0.y >> 16)), 0.f)
        + fmaxf(bf2f((unsigned short)(x1.y >> 16)) + bf2f((unsigned short)(e1.y >> 16)), 0.f)
        + fmaxf(bf2f((unsigned short)(x2.y >> 16)) + bf2f((unsigned short)(e2.y >> 16)), 0.f)
        + fmaxf(bf2f((unsigned short)(x3.y >> 16)) + bf2f((unsigned short)(e3.y >> 16)), 0.f);
  }
  for (; p < p1; p += 2) {
    const int s0 = esrc[p];
    const uint2 x0 = *(const uint2*)(xb + (size_t)s0 * CC + c0);
    const uint2 e0 = *(const uint2*)(ea + (size_t)p * CC + c0);
    a0 += fmaxf(bf2f((unsigned short)x0.x) + bf2f((unsigned short)e0.x), 0.f);
    a1 += fmaxf(bf2f((unsigned short)(x0.x >> 16)) + bf2f((unsigned short)(e0.x >> 16)), 0.f);
    a2 += fmaxf(bf2f((unsigned short)x0.y) + bf2f((unsigned short)e0.y), 0.f);
    a3 += fmaxf(bf2f((unsigned short)(x0.y >> 16)) + bf2f((unsigned short)(e0.y >> 16)), 0.f);
  }

  a0 += __shfl_xor(a0, 32);
  a1 += __shfl_xor(a1, 32);
  a2 += __shfl_xor(a2, 32);
  a3 += __shfl_xor(a3, 32);

  if (half == 0) {
    const uint2 xs = *(const uint2*)(xb + (size_t)n * CC + c0);
    uint2 pk;
    pk.x = (unsigned)f2bf(bf2f((unsigned short)xs.x) + a0)
         | ((unsigned)f2bf(bf2f((unsigned short)(xs.x >> 16)) + a1) << 16);
    pk.y = (unsigned)f2bf(bf2f((unsigned short)xs.y) + a2)
         | ((unsigned)f2bf(bf2f((unsigned short)(xs.y >> 16)) + a3) << 16);
    *(uint2*)(h_out + (size_t)n * CC + c0) = pk;
  }
}

// ---------------- aggregation (fallback: small ws, recompute ea via eidx) ----------------

__global__ __launch_bounds__(256) void agg_fb_kernel(const unsigned short* __restrict__ xb,
                                                     unsigned short* __restrict__ h_out,
                                                     const float* __restrict__ edge_attr,
                                                     const float* __restrict__ We,
                                                     const float* __restrict__ be,
                                                     const int* __restrict__ rowptr,
                                                     const int* __restrict__ eidx,
                                                     const int* __restrict__ esrc) {
  const int tid = threadIdx.x;
  const int c = tid & (CC - 1);
  const int g = tid >> 7;
  const int n = blockIdx.x * 2 + g;

  float wec[ECC];
  #pragma unroll
  for (int k = 0; k < ECC; ++k) wec[k] = We[k * CC + c];
  const float bev = be[c];

  const int p0 = rowptr[n], p1 = rowptr[n + 1];
  float acc = 0.f;
  for (int p = p0; p < p1; ++p) {
    const int e0 = eidx[p];
    const int s0 = esrc[p];
    const float4* ar0 = (const float4*)(edge_attr + (size_t)e0 * ECC);
    const float4 a0 = ar0[0], a1 = ar0[1], a2 = ar0[2], a3 = ar0[3];
    float v0 = bev
      + a0.x*wec[0]  + a0.y*wec[1]  + a0.z*wec[2]  + a0.w*wec[3]
      + a1.x*wec[4]  + a1.y*wec[5]  + a1.z*wec[6]  + a1.w*wec[7]
      + a2.x*wec[8]  + a2.y*wec[9]  + a2.z*wec[10] + a2.w*wec[11]
      + a3.x*wec[12] + a3.y*wec[13] + a3.z*wec[14] + a3.w*wec[15];
    acc += fmaxf(bf2f(xb[(size_t)s0 * CC + c]) + silu_f(v0), 0.f);
  }
  h_out[(size_t)n * CC + c] = f2bf(bf2f(xb[(size_t)n * CC + c]) + acc);
}

// ---------------- fused MLP + residual + LayerNorm (MFMA bf16, 4 waves) ----------------
// FINAL=0: write bf16 in-place to xb. FINAL=1: write f32 to out.
// In-place xb update is safe: all residual reads of this block's rows complete
// before the barrier preceding the store phase, and rows are block-exclusive.

template <int FINAL>
__global__ __launch_bounds__(256) void mlp_kernel(unsigned short* xb,
                                                  const unsigned short* __restrict__ hbuf,
                                                  const unsigned short* __restrict__ wt1,
                                                  const unsigned short* __restrict__ wt2,
                                                  const float* __restrict__ b1,
                                                  const float* __restrict__ b2,
                                                  const float* __restrict__ gamma,
                                                  const float* __restrict__ beta,
                                                  float* __restrict__ out) {
  __shared__ __align__(16) char smem[MTILE * PADC * 2 * 2];  // 43,520 B
  unsigned short* hA = (unsigned short*)smem;                 // [MTILE][PADC]
  unsigned short* tA = (unsigned short*)(smem + MTILE * PADC * 2);
  float* yS = (float*)smem;                                   // [80][YSTR] overlay
  __shared__ float red[MTILE][4][2];

  const int tid = threadIdx.x;
  const int lane = tid & 63;
  const int wv = tid >> 6;
  const int node0 = blockIdx.x * MTILE;
  const int colq = lane & 15;
  const int krow = lane >> 4;
  const int colb = wv * 32;

  for (int idx = tid; idx < MTILE * 16; idx += 256) {
    const int row = idx >> 4, ch = idx & 15;
    *(uint4*)(&hA[row * PADC + ch * 8]) =
        *(const uint4*)(hbuf + (size_t)(node0 + row) * CC + ch * 8);
  }
  __syncthreads();

  bf16x8 bw[2][4];
  #pragma unroll
  for (int n2 = 0; n2 < 2; ++n2)
    #pragma unroll
    for (int kk = 0; kk < 4; ++kk)
      bw[n2][kk] = *(const bf16x8*)(wt1 + (size_t)(colb + n2 * 16 + colq) * CC + kk * 32 + krow * 8);

  f32x4 acc[5][2];
  #pragma unroll
  for (int m = 0; m < 5; ++m) { acc[m][0] = (f32x4)0.f; acc[m][1] = (f32x4)0.f; }

  #pragma unroll
  for (int m = 0; m < 5; ++m)
    #pragma unroll
    for (int kk = 0; kk < 4; ++kk) {
      const bf16x8 a = *(const bf16x8*)(&hA[(m * 16 + colq) * PADC + kk * 32 + krow * 8]);
      acc[m][0] = __builtin_amdgcn_mfma_f32_16x16x32_bf16(a, bw[0][kk], acc[m][0], 0, 0, 0);
      acc[m][1] = __builtin_amdgcn_mfma_f32_16x16x32_bf16(a, bw[1][kk], acc[m][1], 0, 0, 0);
    }

  const float b1v0 = b1[colb + colq], b1v1 = b1[colb + 16 + colq];
  #pragma unroll
  for (int m = 0; m < 5; ++m)
    #pragma unroll
    for (int r = 0; r < 4; ++r) {
      const int row = m * 16 + krow * 4 + r;
      tA[row * PADC + colb + colq]      = f2bf(silu_f(acc[m][0][r] + b1v0));
      tA[row * PADC + colb + 16 + colq] = f2bf(silu_f(acc[m][1][r] + b1v1));
    }
  __syncthreads();

  #pragma unroll
  for (int n2 = 0; n2 < 2; ++n2)
    #pragma unroll
    for (int kk = 0; kk < 4; ++kk)
      bw[n2][kk] = *(const bf16x8*)(wt2 + (size_t)(colb + n2 * 16 + colq) * CC + kk * 32 + krow * 8);

  f32x4 acc2[5][2];
  #pragma unroll
  for (int m = 0; m < 5; ++m) { acc2[m][0] = (f32x4)0.f; acc2[m][1] = (f32x4)0.f; }

  #pragma unroll
  for (int m = 0; m < 5; ++m)
    #pragma unroll
    for (int kk = 0; kk < 4; ++kk) {
      const bf16x8 a = *(const bf16x8*)(&tA[(m * 16 + colq) * PADC + kk * 32 + krow * 8]);
      acc2[m][0] = __builtin_amdgcn_mfma_f32_16x16x32_bf16(a, bw[0][kk], acc2[m][0], 0, 0, 0);
      acc2[m][1] = __builtin_amdgcn_mfma_f32_16x16x32_bf16(a, bw[1][kk], acc2[m][1], 0, 0, 0);
    }

  const float b2v0 = b2[colb + colq], b2v1 = b2[colb + 16 + colq];
  float yv[5][2][4];
  #pragma unroll
  for (int m = 0; m < 5; ++m)
    #pragma unroll
    for (int r = 0; r < 4; ++r) {
      const int row = m * 16 + krow * 4 + r;
      yv[m][0][r] = acc2[m][0][r] + b2v0 + bf2f(xb[(size_t)(node0 + row) * CC + colb + colq]);
      yv[m][1][r] = acc2[m][1][r] + b2v1 + bf2f(xb[(size_t)(node0 + row) * CC + colb + 16 + colq]);
    }

  #pragma unroll
  for (int m = 0; m < 5; ++m)
    #pragma unroll
    for (int r = 0; r < 4; ++r) {
      float s = yv[m][0][r] + yv[m][1][r];
      float s2 = yv[m][0][r] * yv[m][0][r] + yv[m][1][r] * yv[m][1][r];
      #pragma unroll
      for (int off = 1; off < 16; off <<= 1) {
        s  += __shfl_xor(s, off);
        s2 += __shfl_xor(s2, off);
      }
      if (colq == 0) {
        const int row = m * 16 + krow * 4 + r;
        red[row][wv][0] = s;
        red[row][wv][1] = s2;
      }
    }
  __syncthreads();   // red ready; orders all tA/residual reads before yS overlay writes

  const float gm0 = gamma[colb + colq], gm1 = gamma[colb + 16 + colq];
  const float bt0 = beta[colb + colq],  bt1 = beta[colb + 16 + colq];
  #pragma unroll
  for (int m = 0; m < 5; ++m)
    #pragma unroll
    for (int r = 0; r < 4; ++r) {
      const int row = m * 16 + krow * 4 + r;
      const float s  = red[row][0][0] + red[row][1][0] + red[row][2][0] + red[row][3][0];
      const float s2 = red[row][0][1] + red[row][1][1] + red[row][2][1] + red[row][3][1];
      const float mean = s * (1.f / 128.f);
      const float var = s2 * (1.f / 128.f) - mean * mean;
      const float rstd = rsqrtf(var + LN_EPS);
      yS[row * YSTR + colb + colq]      = (yv[m][0][r] - mean) * rstd * gm0 + bt0;
      yS[row * YSTR + colb + 16 + colq] = (yv[m][1][r] - mean) * rstd * gm1 + bt1;
    }
  __syncthreads();

  if (FINAL) {
    // f32 store: 80 rows x 512B = 2560 units of 16B
    float* og = out + (size_t)node0 * CC;
    #pragma unroll
    for (int k = 0; k < 10; ++k) {
      const int u = tid + k * 256;
      const int row = u >> 5, q = u & 31;
      *(float4*)(og + u * 4) = *(const float4*)(&yS[row * YSTR + q * 4]);
    }
  } else {
    // bf16 store in-place: 80 rows x 256B = 1280 units of 16B (8 ch each)
    unsigned short* xg = xb + (size_t)node0 * CC;
    #pragma unroll
    for (int k = 0; k < 5; ++k) {
      const int u = tid + k * 256;
      const int row = u >> 4, ch8 = u & 15;
      const float* yp = &yS[row * YSTR + ch8 * 8];
      uint4 o;
      o.x = (unsigned)f2bf(yp[0]) | ((unsigned)f2bf(yp[1]) << 16);
      o.y = (unsigned)f2bf(yp[2]) | ((unsigned)f2bf(yp[3]) << 16);
      o.z = (unsigned)f2bf(yp[4]) | ((unsigned)f2bf(yp[5]) << 16);
      o.w = (unsigned)f2bf(yp[6]) | ((unsigned)f2bf(yp[7]) << 16);
      *(uint4*)(xg + u * 8) = o;
    }
  }
}

// ---------------- launch ----------------

extern "C" void kernel_launch(void* const* d_in, const int* in_sizes, int n_in,
                              void* d_out, int out_size, void* d_ws, size_t ws_size,
                              hipStream_t stream) {
  const float* x         = (const float*)d_in[0];
  const float* edge_attr = (const float*)d_in[1];
  const float* We        = (const float*)d_in[2];
  const float* be        = (const float*)d_in[3];
  const float* W1        = (const float*)d_in[4];
  const float* b1        = (const float*)d_in[5];
  const float* W2        = (const float*)d_in[6];
  const float* b2        = (const float*)d_in[7];
  const float* gamma     = (const float*)d_in[8];
  const float* beta      = (const float*)d_in[9];
  const int*   ei        = (const int*)d_in[10];
  const int*   src       = ei;        // edge_index[0]
  const int*   dst       = ei + EE;   // edge_index[1]
  float* out = (float*)d_out;

  char* ws = (char*)d_ws;
  unsigned short* xbf    = (unsigned short*)(ws + 0);           // 12,800,000
  unsigned short* hbuf   = (unsigned short*)(ws + 12800000);    // 12,800,000 -> 25,600,000
  unsigned short* wt     = (unsigned short*)(ws + 25600000);    //    262,144 -> 25,862,144
  int*            counts = (int*)(ws + 25862400);               //    200,000 -> 26,062,400
  int*            rowptr = (int*)(ws + 26062592);               //    200,004 -> 26,262,596
  int*            cursor = (int*)(ws + 26262784);               //    200,000 -> 26,462,784
  int*            eidx   = (int*)(ws + 26462976);               //  2,400,000 -> 28,862,976
  int*            esrc   = (int*)(ws + 28863232);               //  2,400,000 -> 31,263,232
  unsigned short* ea     = (unsigned short*)(ws + 31263360);    // 153,600,000 -> 184,863,360
  // webf (8KB) aliases cursor (dead after fill_kernel); scan scratch aliases eidx.
  unsigned short* webf   = (unsigned short*)(ws + 26262784);
  int*            bsum   = (int*)(ws + 26462976);
  int*            boff   = (int*)(ws + 26462976 + 256);
  const bool use_ea = (ws_size >= 184863360ull);
  const int NB = (NN + 1023) / 1024;   // 49

  hipMemsetAsync(counts, 0, (size_t)NN * 4, stream);
  hipMemsetAsync(cursor, 0, (size_t)NN * 4, stream);
  count_kernel<<<(EE + 255) / 256, 256, 0, stream>>>(dst, counts, EE);
  scan1_kernel<<<NB, 1024, 0, stream>>>(counts, bsum, NN);
  scan2_kernel<<<1, 64, 0, stream>>>(bsum, boff, NB);
  scan3_kernel<<<NB, 1024, 0, stream>>>(counts, boff, rowptr, NN);
  fill_kernel<<<(EE + 255) / 256, 256, 0, stream>>>(src, dst, rowptr, cursor, eidx, esrc, EE);
  wconv_kernel<<<LL * 2 * CC, 128, 0, stream>>>(W1, W2, wt);
  xconv_kernel<<<(NN * CC / 8 + 255) / 256, 256, 0, stream>>>(x, xbf);
  if (use_ea) {
    webconv_kernel<<<16, 256, 0, stream>>>(We, webf);
    ea_kernel<<<EE / 64, 256, 0, stream>>>(edge_attr, webf, be, eidx, ea);
  }

  for (int l = 0; l < LL; ++l) {
    if (use_ea)
      agg4_kernel<<<NN / 4, 256, 0, stream>>>(xbf, hbuf, ea, rowptr, esrc);
    else
      agg_fb_kernel<<<NN / 2, 256, 0, stream>>>(xbf, hbuf, edge_attr, We, be, rowptr, eidx, esrc);
    const unsigned short* w1p = wt + ((size_t)l * 2) * CC * CC;
    const unsigned short* w2p = wt + ((size_t)l * 2 + 1) * CC * CC;
    const float* b1p = b1 + (size_t)l * CC;
    const float* b2p = b2 + (size_t)l * CC;
    const float* gmp = gamma + (size_t)l * CC;
    const float* btp = beta + (size_t)l * CC;
    if (l == LL - 1)
      mlp_kernel<1><<<NN / MTILE, 256, 0, stream>>>(xbf, hbuf, w1p, w2p, b1p, b2p, gmp, btp, out);
    else
      mlp_kernel<0><<<NN / MTILE, 256, 0, stream>>>(xbf, hbuf, w1p, w2p, b1p, b2p, gmp, btp, out);
  }
}

// Round 11
// 408.098 us; speedup vs baseline: 1.6230x; 1.0191x over previous
//
#include <hip/hip_runtime.h>

#define NN 50000
#define EE 600000
#define CC 128
#define ECC 16
#define LL 4
#define LN_EPS 1e-5f
#define MTILE 80
#define PADC 136   // LDS row stride in bf16 elems for hA/tA
#define YSTR 132   // f32 stride for yS overlay (2-way-free banks)

typedef float f32x4 __attribute__((ext_vector_type(4)));
typedef short bf16x8 __attribute__((ext_vector_type(8)));

static __device__ __forceinline__ float bf2f(unsigned short u) {
  union { unsigned int i; float f; } v; v.i = ((unsigned int)u) << 16; return v.f;
}
static __device__ __forceinline__ unsigned short f2bf(float f) {
  union { float f; unsigned int i; } v; v.f = f;
  unsigned int b = v.i + 0x7FFFu + ((v.i >> 16) & 1u);
  return (unsigned short)(b >> 16);
}
// pack two f32 -> two bf16 (RNE) in one instruction: lo in [15:0], hi in [31:16]
static __device__ __forceinline__ unsigned pk2bf(float lo, float hi) {
  unsigned r;
  asm("v_cvt_pk_bf16_f32 %0, %1, %2" : "=v"(r) : "v"(lo), "v"(hi));
  return r;
}
static __device__ __forceinline__ float silu_f(float v) {   // fast: rcp instead of IEEE div
  return v * __builtin_amdgcn_rcpf(1.f + __expf(-v));
}

// ---------------- CSR build ----------------

__global__ void count_kernel(const int* __restrict__ dst, int* __restrict__ counts, int E) {
  int e = blockIdx.x * blockDim.x + threadIdx.x;
  if (e < E) atomicAdd(&counts[dst[e]], 1);
}

__global__ __launch_bounds__(1024) void scan1_kernel(const int* __restrict__ counts,
                                                     int* __restrict__ bsum, int n) {
  __shared__ int wsum[16];
  const int tid = threadIdx.x, lane = tid & 63, wv = tid >> 6;
  const int i = blockIdx.x * 1024 + tid;
  int s = (i < n) ? counts[i] : 0;
  #pragma unroll
  for (int off = 1; off < 64; off <<= 1) s += __shfl_xor(s, off);
  if (lane == 0) wsum[wv] = s;
  __syncthreads();
  if (tid == 0) {
    int t = 0;
    #pragma unroll
    for (int j = 0; j < 16; ++j) t += wsum[j];
    bsum[blockIdx.x] = t;
  }
}

__global__ void scan2_kernel(const int* __restrict__ bsum, int* __restrict__ boff, int nb) {
  const int lane = threadIdx.x;   // one wave
  int v = (lane < nb) ? bsum[lane] : 0;
  int incl = v;
  #pragma unroll
  for (int off = 1; off < 64; off <<= 1) {
    int t = __shfl_up(incl, off);
    if (lane >= off) incl += t;
  }
  if (lane < nb) boff[lane] = incl - v;
}

__global__ __launch_bounds__(1024) void scan3_kernel(const int* __restrict__ counts,
                                                     const int* __restrict__ boff,
                                                     int* __restrict__ rowptr, int n) {
  __shared__ int wsum[16];
  const int tid = threadIdx.x, lane = tid & 63, wv = tid >> 6;
  const int i = blockIdx.x * 1024 + tid;
  const int v = (i < n) ? counts[i] : 0;
  int incl = v;
  #pragma unroll
  for (int off = 1; off < 64; off <<= 1) {
    int t = __shfl_up(incl, off);
    if (lane >= off) incl += t;
  }
  if (lane == 63) wsum[wv] = incl;
  __syncthreads();
  if (wv == 0) {
    int vv = (lane < 16) ? wsum[lane] : 0;
    int vi = vv;
    #pragma unroll
    for (int off = 1; off < 16; off <<= 1) {
      int t = __shfl_up(vi, off);
      if (lane >= off) vi += t;
    }
    if (lane < 16) wsum[lane] = vi - vv;   // exclusive wave prefix
  }
  __syncthreads();
  if (i < n) rowptr[i + 1] = boff[blockIdx.x] + wsum[wv] + incl;
  if (i == 0) rowptr[0] = 0;
}

__global__ void fill_kernel(const int* __restrict__ src, const int* __restrict__ dst,
                            const int* __restrict__ rowptr, int* __restrict__ cursor,
                            int* __restrict__ eidx, int* __restrict__ esrc, int E) {
  int e = blockIdx.x * blockDim.x + threadIdx.x;
  if (e < E) {
    const int d = dst[e];
    const int pos = rowptr[d] + atomicAdd(&cursor[d], 1);
    eidx[pos] = e;
    esrc[pos] = src[e];
  }
}

// ---------------- x f32 -> bf16 conversion (once) ----------------

__global__ __launch_bounds__(256) void xconv_kernel(const float* __restrict__ x,
                                                    unsigned short* __restrict__ xb) {
  const int t = blockIdx.x * 256 + threadIdx.x;   // 8 elems each
  if (t >= NN * CC / 8) return;
  const float4 a = ((const float4*)x)[t * 2];
  const float4 b = ((const float4*)x)[t * 2 + 1];
  uint4 o;
  o.x = pk2bf(a.x, a.y);
  o.y = pk2bf(a.z, a.w);
  o.z = pk2bf(b.x, b.y);
  o.w = pk2bf(b.z, b.w);
  ((uint4*)xb)[t] = o;
}

// ---------------- We B-fragment prep (bf16, MFMA fragment order) ----------------

__global__ void webconv_kernel(const float* __restrict__ We, unsigned short* __restrict__ webf) {
  const int t = blockIdx.x * blockDim.x + threadIdx.x;
  if (t >= 8 * 64 * 8) return;
  const int j = t & 7, l = (t >> 3) & 63, cg = t >> 9;
  const int k = (l >> 4) * 8 + j, c = cg * 16 + (l & 15);
  webf[t] = (k < 16) ? f2bf(We[k * CC + c]) : (unsigned short)0;
}

// ---------------- ea precompute via MFMA (CSR order, bf16, coalesced stores) ----------------

__global__ __launch_bounds__(256) void ea_kernel(const float* __restrict__ edge_attr,
                                                 const unsigned short* __restrict__ webf,
                                                 const float* __restrict__ be,
                                                 const int* __restrict__ eidx,
                                                 unsigned short* __restrict__ ea) {
  __shared__ float er[64][20];             // pad 20: 16B-aligned float4 rows
  __shared__ unsigned short eaT[64 * 132]; // repack tile, stride 132 shorts
  const int tid = threadIdx.x;
  const int lane = tid & 63, wv = tid >> 6;

  bf16x8 bw[8];
  #pragma unroll
  for (int cg = 0; cg < 8; ++cg)
    bw[cg] = *(const bf16x8*)(webf + cg * 512 + lane * 8);
  float bev[8];
  #pragma unroll
  for (int cg = 0; cg < 8; ++cg) bev[cg] = be[cg * 16 + (lane & 15)];

  const int base = blockIdx.x * 64;
  {
    const int r = tid >> 2, q = tid & 3;
    const int e = eidx[base + r];
    *(float4*)(&er[r][q * 4]) = *(const float4*)(edge_attr + (size_t)e * ECC + q * 4);
  }
  __syncthreads();

  const int arow = wv * 16 + (lane & 15);
  const int ko = lane >> 4;
  union { unsigned short u[8]; unsigned v32[4]; bf16x8 v; } afu;
  if (ko < 2) {
    const float* ep = &er[arow][ko * 8];
    afu.v32[0] = pk2bf(ep[0], ep[1]);
    afu.v32[1] = pk2bf(ep[2], ep[3]);
    afu.v32[2] = pk2bf(ep[4], ep[5]);
    afu.v32[3] = pk2bf(ep[6], ep[7]);
  } else {
    #pragma unroll
    for (int j = 0; j < 4; ++j) afu.v32[j] = 0;
  }

  f32x4 acc[8];
  #pragma unroll
  for (int cg = 0; cg < 8; ++cg) {
    acc[cg] = (f32x4)0.f;
    acc[cg] = __builtin_amdgcn_mfma_f32_16x16x32_bf16(afu.v, bw[cg], acc[cg], 0, 0, 0);
  }

  const int rl0 = wv * 16 + ko * 4;
  const int cb = lane & 15;
  // epilogue: silu + cvt_pk pairs over cg, u16 LDS writes
  #pragma unroll
  for (int cg = 0; cg < 8; cg += 2)
    #pragma unroll
    for (int r = 0; r < 4; ++r) {
      const float v0 = silu_f(acc[cg][r] + bev[cg]);
      const float v1 = silu_f(acc[cg + 1][r] + bev[cg + 1]);
      const unsigned pk = pk2bf(v0, v1);
      unsigned short* rp = &eaT[(rl0 + r) * 132 + cb];
      rp[cg * 16]       = (unsigned short)pk;
      rp[(cg + 1) * 16] = (unsigned short)(pk >> 16);
    }
  __syncthreads();

  uint4* eg = (uint4*)(ea + (size_t)base * CC);
  #pragma unroll
  for (int k = 0; k < 4; ++k) {
    const int u = tid + k * 256;
    const int row = u >> 4, ch = u & 15;
    eg[u] = *(const uint4*)(&eaT[row * 132 + ch * 8]);
  }
}

// ---------------- weight transpose+cast: wt[l][mat][c][k] = bf16(W[l][k][c]) ----------------

__global__ __launch_bounds__(128) void wconv_kernel(const float* __restrict__ W1,
                                                    const float* __restrict__ W2,
                                                    unsigned short* __restrict__ wt) {
  const int b = blockIdx.x;
  const int c = b & (CC - 1);
  const int mat = (b >> 7) & 1;
  const int l = b >> 8;
  const float* W = (mat ? W2 : W1) + (size_t)l * CC * CC;
  unsigned short* o = wt + ((size_t)l * 2 + mat) * CC * CC + (size_t)c * CC;
  const int k = threadIdx.x;
  o[k] = f2bf(W[(size_t)k * CC + c]);
}

// ---------------- aggregation: half-wave per edge, 4 bf16 channels/lane ----------------

__global__ __launch_bounds__(256) void agg4_kernel(const unsigned short* __restrict__ xb,
                                                   unsigned short* __restrict__ h_out,
                                                   const unsigned short* __restrict__ ea,
                                                   const int* __restrict__ rowptr,
                                                   const int* __restrict__ esrc) {
  const int tid = threadIdx.x;
  const int lane = tid & 63;
  const int half = lane >> 5;
  const int l32 = lane & 31;
  const int c0 = l32 * 4;
  const int wv = tid >> 6;
  const int n = blockIdx.x * 4 + wv;

  const int p0 = rowptr[n], p1 = rowptr[n + 1];
  float a0 = 0.f, a1 = 0.f, a2 = 0.f, a3 = 0.f;

  int p = p0 + half;
  for (; p + 6 < p1; p += 8) {
    const int s0 = esrc[p], s1 = esrc[p + 2], s2 = esrc[p + 4], s3 = esrc[p + 6];
    const uint2 x0 = *(const uint2*)(xb + (size_t)s0 * CC + c0);
    const uint2 x1 = *(const uint2*)(xb + (size_t)s1 * CC + c0);
    const uint2 x2 = *(const uint2*)(xb + (size_t)s2 * CC + c0);
    const uint2 x3 = *(const uint2*)(xb + (size_t)s3 * CC + c0);
    const uint2 e0 = *(const uint2*)(ea + (size_t)p * CC + c0);
    const uint2 e1 = *(const uint2*)(ea + (size_t)(p + 2) * CC + c0);
    const uint2 e2 = *(const uint2*)(ea + (size_t)(p + 4) * CC + c0);
    const uint2 e3 = *(const uint2*)(ea + (size_t)(p + 6) * CC + c0);
    a0 += fmaxf(bf2f((unsigned short)x0.x) + bf2f((unsigned short)e0.x), 0.f)
        + fmaxf(bf2f((unsigned short)x1.x) + bf2f((unsigned short)e1.x), 0.f)
        + fmaxf(bf2f((unsigned short)x2.x) + bf2f((unsigned short)e2.x), 0.f)
        + fmaxf(bf2f((unsigned short)x3.x) + bf2f((unsigned short)e3.x), 0.f);
    a1 += fmaxf(bf2f((unsigned short)(x0.x >> 16)) + bf2f((unsigned short)(e0.x >> 16)), 0.f)
        + fmaxf(bf2f((unsigned short)(x1.x >> 16)) + bf2f((unsigned short)(e1.x >> 16)), 0.f)
        + fmaxf(bf2f((unsigned short)(x2.x >> 16)) + bf2f((unsigned short)(e2.x >> 16)), 0.f)
        + fmaxf(bf2f((unsigned short)(x3.x >> 16)) + bf2f((unsigned short)(e3.x >> 16)), 0.f);
    a2 += fmaxf(bf2f((unsigned short)x0.y) + bf2f((unsigned short)e0.y), 0.f)
        + fmaxf(bf2f((unsigned short)x1.y) + bf2f((unsigned short)e1.y), 0.f)
        + fmaxf(bf2f((unsigned short)x2.y) + bf2f((unsigned short)e2.y), 0.f)
        + fmaxf(bf2f((unsigned short)x3.y) + bf2f((unsigned short)e3.y), 0.f);
    a3 += fmaxf(bf2f((unsigned short)(x0.y >> 16)) + bf2f((unsigned short)(e0.y >> 16)), 0.f)
        + fmaxf(bf2f((unsigned short)(x1.y >> 16)) + bf2f((unsigned short)(e1.y >> 16)), 0.f)
        + fmaxf(bf2f((unsigned short)(x2.y >> 16)) + bf2f((unsigned short)(e2.y >> 16)), 0.f)
        + fmaxf(bf2f((unsigned short)(x3.y >> 16)) + bf2f((unsigned short)(e3.y >> 16)), 0.f);
  }
  for (; p < p1; p += 2) {
    const int s0 = esrc[p];
    const uint2 x0 = *(const uint2*)(xb + (size_t)s0 * CC + c0);
    const uint2 e0 = *(const uint2*)(ea + (size_t)p * CC + c0);
    a0 += fmaxf(bf2f((unsigned short)x0.x) + bf2f((unsigned short)e0.x), 0.f);
    a1 += fmaxf(bf2f((unsigned short)(x0.x >> 16)) + bf2f((unsigned short)(e0.x >> 16)), 0.f);
    a2 += fmaxf(bf2f((unsigned short)x0.y) + bf2f((unsigned short)e0.y), 0.f);
    a3 += fmaxf(bf2f((unsigned short)(x0.y >> 16)) + bf2f((unsigned short)(e0.y >> 16)), 0.f);
  }

  a0 += __shfl_xor(a0, 32);
  a1 += __shfl_xor(a1, 32);
  a2 += __shfl_xor(a2, 32);
  a3 += __shfl_xor(a3, 32);

  if (half == 0) {
    const uint2 xs = *(const uint2*)(xb + (size_t)n * CC + c0);
    uint2 pk;
    pk.x = pk2bf(bf2f((unsigned short)xs.x) + a0, bf2f((unsigned short)(xs.x >> 16)) + a1);
    pk.y = pk2bf(bf2f((unsigned short)xs.y) + a2, bf2f((unsigned short)(xs.y >> 16)) + a3);
    *(uint2*)(h_out + (size_t)n * CC + c0) = pk;
  }
}

// ---------------- aggregation (fallback: small ws, recompute ea via eidx) ----------------

__global__ __launch_bounds__(256) void agg_fb_kernel(const unsigned short* __restrict__ xb,
                                                     unsigned short* __restrict__ h_out,
                                                     const float* __restrict__ edge_attr,
                                                     const float* __restrict__ We,
                                                     const float* __restrict__ be,
                                                     const int* __restrict__ rowptr,
                                                     const int* __restrict__ eidx,
                                                     const int* __restrict__ esrc) {
  const int tid = threadIdx.x;
  const int c = tid & (CC - 1);
  const int g = tid >> 7;
  const int n = blockIdx.x * 2 + g;

  float wec[ECC];
  #pragma unroll
  for (int k = 0; k < ECC; ++k) wec[k] = We[k * CC + c];
  const float bev = be[c];

  const int p0 = rowptr[n], p1 = rowptr[n + 1];
  float acc = 0.f;
  for (int p = p0; p < p1; ++p) {
    const int e0 = eidx[p];
    const int s0 = esrc[p];
    const float4* ar0 = (const float4*)(edge_attr + (size_t)e0 * ECC);
    const float4 a0 = ar0[0], a1 = ar0[1], a2 = ar0[2], a3 = ar0[3];
    float v0 = bev
      + a0.x*wec[0]  + a0.y*wec[1]  + a0.z*wec[2]  + a0.w*wec[3]
      + a1.x*wec[4]  + a1.y*wec[5]  + a1.z*wec[6]  + a1.w*wec[7]
      + a2.x*wec[8]  + a2.y*wec[9]  + a2.z*wec[10] + a2.w*wec[11]
      + a3.x*wec[12] + a3.y*wec[13] + a3.z*wec[14] + a3.w*wec[15];
    acc += fmaxf(bf2f(xb[(size_t)s0 * CC + c]) + silu_f(v0), 0.f);
  }
  h_out[(size_t)n * CC + c] = f2bf(bf2f(xb[(size_t)n * CC + c]) + acc);
}

// ---------------- fused MLP + residual + LayerNorm (MFMA bf16, 4 waves) ----------------
// FINAL=0: write bf16 in-place to xb. FINAL=1: write f32 to out.

template <int FINAL>
__global__ __launch_bounds__(256) void mlp_kernel(unsigned short* xb,
                                                  const unsigned short* __restrict__ hbuf,
                                                  const unsigned short* __restrict__ wt1,
                                                  const unsigned short* __restrict__ wt2,
                                                  const float* __restrict__ b1,
                                                  const float* __restrict__ b2,
                                                  const float* __restrict__ gamma,
                                                  const float* __restrict__ beta,
                                                  float* __restrict__ out) {
  __shared__ __align__(16) char smem[MTILE * PADC * 2 * 2];  // 43,520 B
  unsigned short* hA = (unsigned short*)smem;                 // [MTILE][PADC]
  unsigned short* tA = (unsigned short*)(smem + MTILE * PADC * 2);
  float* yS = (float*)smem;                                   // [80][YSTR] overlay
  __shared__ float red[MTILE][4][2];

  const int tid = threadIdx.x;
  const int lane = tid & 63;
  const int wv = tid >> 6;
  const int node0 = blockIdx.x * MTILE;
  const int colq = lane & 15;
  const int krow = lane >> 4;
  const int colb = wv * 32;

  for (int idx = tid; idx < MTILE * 16; idx += 256) {
    const int row = idx >> 4, ch = idx & 15;
    *(uint4*)(&hA[row * PADC + ch * 8]) =
        *(const uint4*)(hbuf + (size_t)(node0 + row) * CC + ch * 8);
  }
  __syncthreads();

  bf16x8 bw[2][4];
  #pragma unroll
  for (int n2 = 0; n2 < 2; ++n2)
    #pragma unroll
    for (int kk = 0; kk < 4; ++kk)
      bw[n2][kk] = *(const bf16x8*)(wt1 + (size_t)(colb + n2 * 16 + colq) * CC + kk * 32 + krow * 8);

  f32x4 acc[5][2];
  #pragma unroll
  for (int m = 0; m < 5; ++m) { acc[m][0] = (f32x4)0.f; acc[m][1] = (f32x4)0.f; }

  #pragma unroll
  for (int m = 0; m < 5; ++m)
    #pragma unroll
    for (int kk = 0; kk < 4; ++kk) {
      const bf16x8 a = *(const bf16x8*)(&hA[(m * 16 + colq) * PADC + kk * 32 + krow * 8]);
      acc[m][0] = __builtin_amdgcn_mfma_f32_16x16x32_bf16(a, bw[0][kk], acc[m][0], 0, 0, 0);
      acc[m][1] = __builtin_amdgcn_mfma_f32_16x16x32_bf16(a, bw[1][kk], acc[m][1], 0, 0, 0);
    }

  const float b1v0 = b1[colb + colq], b1v1 = b1[colb + 16 + colq];
  #pragma unroll
  for (int m = 0; m < 5; ++m)
    #pragma unroll
    for (int r = 0; r < 4; ++r) {
      const int row = m * 16 + krow * 4 + r;
      const unsigned pk = pk2bf(silu_f(acc[m][0][r] + b1v0), silu_f(acc[m][1][r] + b1v1));
      tA[row * PADC + colb + colq]      = (unsigned short)pk;
      tA[row * PADC + colb + 16 + colq] = (unsigned short)(pk >> 16);
    }
  __syncthreads();

  #pragma unroll
  for (int n2 = 0; n2 < 2; ++n2)
    #pragma unroll
    for (int kk = 0; kk < 4; ++kk)
      bw[n2][kk] = *(const bf16x8*)(wt2 + (size_t)(colb + n2 * 16 + colq) * CC + kk * 32 + krow * 8);

  f32x4 acc2[5][2];
  #pragma unroll
  for (int m = 0; m < 5; ++m) { acc2[m][0] = (f32x4)0.f; acc2[m][1] = (f32x4)0.f; }

  #pragma unroll
  for (int m = 0; m < 5; ++m)
    #pragma unroll
    for (int kk = 0; kk < 4; ++kk) {
      const bf16x8 a = *(const bf16x8*)(&tA[(m * 16 + colq) * PADC + kk * 32 + krow * 8]);
      acc2[m][0] = __builtin_amdgcn_mfma_f32_16x16x32_bf16(a, bw[0][kk], acc2[m][0], 0, 0, 0);
      acc2[m][1] = __builtin_amdgcn_mfma_f32_16x16x32_bf16(a, bw[1][kk], acc2[m][1], 0, 0, 0);
    }

  const float b2v0 = b2[colb + colq], b2v1 = b2[colb + 16 + colq];
  float yv[5][2][4];
  #pragma unroll
  for (int m = 0; m < 5; ++m)
    #pragma unroll
    for (int r = 0; r < 4; ++r) {
      const int row = m * 16 + krow * 4 + r;
      yv[m][0][r] = acc2[m][0][r] + b2v0 + bf2f(xb[(size_t)(node0 + row) * CC + colb + colq]);
      yv[m][1][r] = acc2[m][1][r] + b2v1 + bf2f(xb[(size_t)(node0 + row) * CC + colb + 16 + colq]);
    }

  #pragma unroll
  for (int m = 0; m < 5; ++m)
    #pragma unroll
    for (int r = 0; r < 4; ++r) {
      float s = yv[m][0][r] + yv[m][1][r];
      float s2 = yv[m][0][r] * yv[m][0][r] + yv[m][1][r] * yv[m][1][r];
      #pragma unroll
      for (int off = 1; off < 16; off <<= 1) {
        s  += __shfl_xor(s, off);
        s2 += __shfl_xor(s2, off);
      }
      if (colq == 0) {
        const int row = m * 16 + krow * 4 + r;
        red[row][wv][0] = s;
        red[row][wv][1] = s2;
      }
    }
  __syncthreads();   // red ready; orders all tA/residual reads before yS overlay writes

  const float gm0 = gamma[colb + colq], gm1 = gamma[colb + 16 + colq];
  const float bt0 = beta[colb + colq],  bt1 = beta[colb + 16 + colq];
  #pragma unroll
  for (int m = 0; m < 5; ++m)
    #pragma unroll
    for (int r = 0; r < 4; ++r) {
      const int row = m * 16 + krow * 4 + r;
      const float s  = red[row][0][0] + red[row][1][0] + red[row][2][0] + red[row][3][0];
      const float s2 = red[row][0][1] + red[row][1][1] + red[row][2][1] + red[row][3][1];
      const float mean = s * (1.f / 128.f);
      const float var = s2 * (1.f / 128.f) - mean * mean;
      const float rstd = rsqrtf(var + LN_EPS);
      yS[row * YSTR + colb + colq]      = (yv[m][0][r] - mean) * rstd * gm0 + bt0;
      yS[row * YSTR + colb + 16 + colq] = (yv[m][1][r] - mean) * rstd * gm1 + bt1;
    }
  __syncthreads();

  if (FINAL) {
    float* og = out + (size_t)node0 * CC;
    #pragma unroll
    for (int k = 0; k < 10; ++k) {
      const int u = tid + k * 256;
      const int row = u >> 5, q = u & 31;
      *(float4*)(og + u * 4) = *(const float4*)(&yS[row * YSTR + q * 4]);
    }
  } else {
    unsigned short* xg = xb + (size_t)node0 * CC;
    #pragma unroll
    for (int k = 0; k < 5; ++k) {
      const int u = tid + k * 256;
      const int row = u >> 4, ch8 = u & 15;
      const float* yp = &yS[row * YSTR + ch8 * 8];
      uint4 o;
      o.x = pk2bf(yp[0], yp[1]);
      o.y = pk2bf(yp[2], yp[3]);
      o.z = pk2bf(yp[4], yp[5]);
      o.w = pk2bf(yp[6], yp[7]);
      *(uint4*)(xg + u * 8) = o;
    }
  }
}

// ---------------- launch ----------------

extern "C" void kernel_launch(void* const* d_in, const int* in_sizes, int n_in,
                              void* d_out, int out_size, void* d_ws, size_t ws_size,
                              hipStream_t stream) {
  const float* x         = (const float*)d_in[0];
  const float* edge_attr = (const float*)d_in[1];
  const float* We        = (const float*)d_in[2];
  const float* be        = (const float*)d_in[3];
  const float* W1        = (const float*)d_in[4];
  const float* b1        = (const float*)d_in[5];
  const float* W2        = (const float*)d_in[6];
  const float* b2        = (const float*)d_in[7];
  const float* gamma     = (const float*)d_in[8];
  const float* beta      = (const float*)d_in[9];
  const int*   ei        = (const int*)d_in[10];
  const int*   src       = ei;        // edge_index[0]
  const int*   dst       = ei + EE;   // edge_index[1]
  float* out = (float*)d_out;

  char* ws = (char*)d_ws;
  unsigned short* xbf    = (unsigned short*)(ws + 0);           // 12,800,000
  unsigned short* hbuf   = (unsigned short*)(ws + 12800000);    // 12,800,000 -> 25,600,000
  unsigned short* wt     = (unsigned short*)(ws + 25600000);    //    262,144 -> 25,862,144
  int*            counts = (int*)(ws + 25862400);               //    200,000 -> 26,062,400
  int*            rowptr = (int*)(ws + 26062592);               //    200,004 -> 26,262,596
  int*            cursor = (int*)(ws + 26262784);               //    200,000 -> 26,462,784
  int*            eidx   = (int*)(ws + 26462976);               //  2,400,000 -> 28,862,976
  int*            esrc   = (int*)(ws + 28863232);               //  2,400,000 -> 31,263,232
  unsigned short* ea     = (unsigned short*)(ws + 31263360);    // 153,600,000 -> 184,863,360
  unsigned short* webf   = (unsigned short*)(ws + 26262784);    // aliases cursor (dead after fill)
  int*            bsum   = (int*)(ws + 26462976);               // aliases eidx (dead until fill)
  int*            boff   = (int*)(ws + 26462976 + 256);
  const bool use_ea = (ws_size >= 184863360ull);
  const int NB = (NN + 1023) / 1024;   // 49

  hipMemsetAsync(counts, 0, (size_t)NN * 4, stream);
  hipMemsetAsync(cursor, 0, (size_t)NN * 4, stream);
  count_kernel<<<(EE + 255) / 256, 256, 0, stream>>>(dst, counts, EE);
  scan1_kernel<<<NB, 1024, 0, stream>>>(counts, bsum, NN);
  scan2_kernel<<<1, 64, 0, stream>>>(bsum, boff, NB);
  scan3_kernel<<<NB, 1024, 0, stream>>>(counts, boff, rowptr, NN);
  fill_kernel<<<(EE + 255) / 256, 256, 0, stream>>>(src, dst, rowptr, cursor, eidx, esrc, EE);
  wconv_kernel<<<LL * 2 * CC, 128, 0, stream>>>(W1, W2, wt);
  xconv_kernel<<<(NN * CC / 8 + 255) / 256, 256, 0, stream>>>(x, xbf);
  if (use_ea) {
    webconv_kernel<<<16, 256, 0, stream>>>(We, webf);
    ea_kernel<<<EE / 64, 256, 0, stream>>>(edge_attr, webf, be, eidx, ea);
  }

  for (int l = 0; l < LL; ++l) {
    if (use_ea)
      agg4_kernel<<<NN / 4, 256, 0, stream>>>(xbf, hbuf, ea, rowptr, esrc);
    else
      agg_fb_kernel<<<NN / 2, 256, 0, stream>>>(xbf, hbuf, edge_attr, We, be, rowptr, eidx, esrc);
    const unsigned short* w1p = wt + ((size_t)l * 2) * CC * CC;
    const unsigned short* w2p = wt + ((size_t)l * 2 + 1) * CC * CC;
    const float* b1p = b1 + (size_t)l * CC;
    const float* b2p = b2 + (size_t)l * CC;
    const float* gmp = gamma + (size_t)l * CC;
    const float* btp = beta + (size_t)l * CC;
    if (l == LL - 1)
      mlp_kernel<1><<<NN / MTILE, 256, 0, stream>>>(xbf, hbuf, w1p, w2p, b1p, b2p, gmp, btp, out);
    else
      mlp_kernel<0><<<NN / MTILE, 256, 0, stream>>>(xbf, hbuf, w1p, w2p, b1p, b2p, gmp, btp, out);
  }
}